// Round 4
// baseline (766.661 us; speedup 1.0000x reference)
//
#include <hip/hip_runtime.h>
#include <hip/hip_bf16.h>

#define D_IN 128
#define D_EMB 64

typedef float f32x2 __attribute__((ext_vector_type(2)));
typedef float f32x4v __attribute__((ext_vector_type(4)));
typedef short bf16x8 __attribute__((ext_vector_type(8)));   // 8 bf16 = 4 VGPRs (guide §3)

static __device__ __forceinline__ unsigned short f2bf(float f) {
  __hip_bfloat16 h = __float2bfloat16(f);
  return *(unsigned short*)&h;
}

// ---- MFMA weight prep: W[64][K] fp32 -> packed bf16 B-fragments.
// frag index tid=(s*4+ct)*64+lane holds W[ct*16+(lane&15)][s*32+(lane>>4)*8 + j], j=0..7
__global__ __launch_bounds__(256) void wprep_mfma_k(const float* __restrict__ W,
                                                    unsigned short* __restrict__ out,
                                                    int K) {
  int tid = blockIdx.x * 256 + threadIdx.x;
  int total = (K / 32) * 4 * 64;
  if (tid >= total) return;
  int lane = tid & 63;
  int ct = (tid >> 6) & 3;
  int s = tid >> 8;
  int row = ct * 16 + (lane & 15);
  int kk = s * 32 + (lane >> 4) * 8;
  unsigned short tmp[8];
#pragma unroll
  for (int j = 0; j < 8; j++) tmp[j] = f2bf(W[row * K + kk + j]);
  *(uint4*)&out[(size_t)tid * 8] = *(uint4*)tmp;
}

// ==== CSR build, round-12 design (3rd submit; rounds 13/14 were infra fails) ====
// Round-11 evidence: fill_bkt_k's scattered 4B csr stores cost ~46B HBM write
// EACH (WRITE_SIZE 93MB for an 8MB payload) even with a ~1MB-per-XCD working
// set -> partial-line stores do NOT write-combine in L2; they are forwarded
// memory-side. Conclusion: the per-node scatter must happen in LDS, and the
// only global csr write must be a linear full-line copy.
// Pipeline: bhist/bscan/bfill (8-way XCD bucketing, proven) -> deg3 (per-sub
// LDS histogram, atomic-free coalesced deg) -> rowPtr scan -> scat3 (per-sub
// LDS counting scatter + coalesced flush).

// Per-block histogram of dst>>14, written TRANSPOSED: bh[b*1024 + blockIdx].
// Grid must be 1024 blocks x 2048-edge chunks (E = 2M). Unused entries stay 0
// from the workspace memset, so the scan remains correct if E < 2M.
__global__ __launch_bounds__(256) void bhist_k(const int* __restrict__ dst,
                                               int* __restrict__ bh, int E) {
  __shared__ int h[8];
  const int t = threadIdx.x;
  if (t < 8) h[t] = 0;
  __syncthreads();
  const int base = blockIdx.x * 2048;
#pragma unroll
  for (int j = 0; j < 8; j++) {
    int e = base + j * 256 + t;
    if (e < E) atomicAdd(&h[dst[e] >> 14], 1);
  }
  __syncthreads();
  if (t < 8) bh[t * 1024 + blockIdx.x] = h[t];
}

// Single-block exclusive scan of bh[8192] in place (order: bucket-major,
// block-minor) -> bh[b*1024+i] = write base for (bucket b, block i).
// Also emits bbase[0..7] = bucket starts, bbase[8] = E.
__global__ __launch_bounds__(256) void bscan_k(int* __restrict__ bh,
                                               int* __restrict__ bbase) {
  __shared__ int s[256], s2[256];
  const int t = threadIdx.x;
  int v[32];
  int sum = 0;
#pragma unroll
  for (int j = 0; j < 32; j++) { v[j] = bh[t * 32 + j]; sum += v[j]; }
  s[t] = sum;
  __syncthreads();
  int* in = s;
  int* out = s2;
  for (int st = 1; st < 256; st <<= 1) {
    out[t] = in[t] + (t >= st ? in[t - st] : 0);
    __syncthreads();
    int* tmp = in; in = out; out = tmp;
  }
  const int tot = in[255];
  int run = in[t] - sum;   // exclusive prefix of this thread's 32-chunk
#pragma unroll
  for (int j = 0; j < 32; j++) { bh[t * 32 + j] = run; run += v[j]; }
  __syncthreads();   // bh writes visible within block (same CU/L1)
  if (t < 8) bbase[t] = bh[t * 1024];
  if (t == 8) bbase[8] = tot;
}

// Bin edges into buckets. Per-block bases are deterministic (from bscan);
// only the order WITHIN (block,bucket) is LDS-atomic-nondeterministic, which
// downstream tolerates (csr order within a node was already nondeterministic).
__global__ __launch_bounds__(256) void bfill_k(const int* __restrict__ src,
                                               const int* __restrict__ dst,
                                               const int* __restrict__ bh,
                                               unsigned int* __restrict__ bkt, int E) {
  __shared__ int hbase[8], hcur[8];
  const int t = threadIdx.x;
  if (t < 8) { hbase[t] = bh[t * 1024 + blockIdx.x]; hcur[t] = 0; }
  __syncthreads();
  const int base = blockIdx.x * 2048;
#pragma unroll
  for (int j = 0; j < 8; j++) {
    int e = base + j * 256 + t;
    if (e < E) {
      int d = dst[e];
      int b = d >> 14;
      int pos = hbase[b] + atomicAdd(&hcur[b], 1);
      bkt[pos] = ((unsigned)(d & 16383) << 17) | (unsigned)src[e];
    }
  }
}

// Per-sub degree count: block = (partition p = blockIdx&7 -> XCD p, sub s =
// blockIdx>>3). Streams partition p's bucket (~1MB, L2-resident; all 32 blocks
// of partition p share the same lines), filters its 512 nodes (1/32 of lanes
// match -> LDS atomics rare), writes deg coalesced + atomic-free.
__global__ __launch_bounds__(256) void deg3_k(const unsigned int* __restrict__ bkt,
                                              const int* __restrict__ bbase,
                                              int* __restrict__ deg, int N) {
  __shared__ int h[512];
  const int t = threadIdx.x;
  h[t] = 0;
  h[t + 256] = 0;
  __syncthreads();
  const int p = blockIdx.x & 7;
  const int s = blockIdx.x >> 3;
  const int lo = bbase[p], hi = bbase[p + 1];
  for (int i = lo + t; i < hi; i += 256) {
    unsigned v = bkt[i];
    unsigned dlocal = v >> 17;
    if ((int)(dlocal >> 9) == s) atomicAdd(&h[dlocal & 511], 1);
  }
  __syncthreads();
  const int node0 = p * (N >> 3) + s * 512;
  deg[node0 + t] = h[t];
  deg[node0 + t + 256] = h[t + 256];
}

__global__ __launch_bounds__(256) void blocksum_k(const int* __restrict__ deg,
                                                  int* __restrict__ bsum) {
  __shared__ int sm[256];
  int t = threadIdx.x;
  sm[t] = deg[blockIdx.x * 256 + t];
  __syncthreads();
  for (int s = 128; s > 0; s >>= 1) {
    if (t < s) sm[t] += sm[t + s];
    __syncthreads();
  }
  if (t == 0) bsum[blockIdx.x] = sm[0];
}

// single block: exclusive scan of 512 block sums (in place)
__global__ __launch_bounds__(256) void scanbsum_k(int* __restrict__ bsum) {
  __shared__ int a[512], b[512];
  int t = threadIdx.x;
  a[t] = bsum[t];
  a[t + 256] = bsum[t + 256];
  __syncthreads();
  int* in = a;
  int* out = b;
  for (int st = 1; st < 512; st <<= 1) {
    for (int i = t; i < 512; i += 256) out[i] = in[i] + (i >= st ? in[i - st] : 0);
    __syncthreads();
    int* tmp = in; in = out; out = tmp;
  }
  for (int i = t; i < 512; i += 256) bsum[i] = (i == 0) ? 0 : in[i - 1];
}

// per-block inclusive scan of deg + block offset -> rowPtr (exclusive), fused invdeg
__global__ __launch_bounds__(256) void rowptr_k(const int* __restrict__ deg,
                                                const int* __restrict__ bsumEx,
                                                int* __restrict__ rowPtr,
                                                float* __restrict__ invdeg) {
  __shared__ int a[256], b[256];
  int t = threadIdx.x;
  int i = blockIdx.x * 256 + t;
  int d = deg[i];
  a[t] = d;
  __syncthreads();
  int* in = a;
  int* out = b;
  for (int st = 1; st < 256; st <<= 1) {
    out[t] = in[t] + (t >= st ? in[t - st] : 0);
    __syncthreads();
    int* tmp = in; in = out; out = tmp;
  }
  int incl = in[t] + bsumEx[blockIdx.x];
  rowPtr[i + 1] = incl;
  invdeg[i] = 1.0f / fmaxf((float)d, 1.0f);
  if (i == 0) rowPtr[0] = 0;
}

// Per-sub LDS counting scatter. Same block mapping as deg3_k. Scatters the
// sub's ~8192 src values into a 47KB LDS buffer (cap 12032 = +42 sigma for
// Binomial(2M, 1/256); impossible-overflow fallback keeps correctness), then
// flushes LDS->csr as one contiguous coalesced write. WRITE_SIZE ~= payload.
#define CSR_CAP 12032
__global__ __launch_bounds__(256) void scat3_k(const unsigned int* __restrict__ bkt,
                                               const int* __restrict__ bbase,
                                               const int* __restrict__ rowPtr,
                                               int* __restrict__ csr, int N) {
  __shared__ int cur[512];
  __shared__ int cbuf[CSR_CAP];
  const int t = threadIdx.x;
  const int p = blockIdx.x & 7;
  const int s = blockIdx.x >> 3;
  const int node0 = p * (N >> 3) + s * 512;
  const int base0 = rowPtr[node0];
  cur[t] = rowPtr[node0 + t] - base0;
  cur[t + 256] = rowPtr[node0 + t + 256] - base0;
  __syncthreads();
  const int lo = bbase[p], hi = bbase[p + 1];
  for (int i = lo + t; i < hi; i += 256) {
    unsigned v = bkt[i];
    unsigned dlocal = v >> 17;
    if ((int)(dlocal >> 9) == s) {
      int pos = atomicAdd(&cur[dlocal & 511], 1);
      int sval = (int)(v & 0x1FFFFu);
      if (pos < CSR_CAP) cbuf[pos] = sval;
      else csr[base0 + pos] = sval;   // never taken for uniform-random input
    }
  }
  __syncthreads();
  const int cnt = rowPtr[node0 + 512] - base0;
  const int lim = cnt < CSR_CAP ? cnt : CSR_CAP;
  for (int i = t; i < lim; i += 256) csr[base0 + i] = cbuf[i];
}

// ---- MFMA GEMM: 64 nodes/block, 4 waves x 16-node tile, 16x16x32 bf16 MFMA.
// out1 = fp8_e4m3(x @ W1.T) ; DUAL: out2 = fp32(bias2 + x @ W2.T)
// A-frag: A[m=lane&15][k=quad*8+j] (guide-verified). B pre-packed by wprep_mfma_k.
// C/D: col=lane&15, row=quad*4+reg (m89-verified).
template <int K, int DUAL>
__global__ __launch_bounds__(256) void gemm_mfma_k(const float4* __restrict__ x4,
                                                   const unsigned short* __restrict__ wb1,
                                                   const unsigned short* __restrict__ wb2,
                                                   const float* __restrict__ bias2,
                                                   unsigned char* __restrict__ out1,
                                                   float* __restrict__ out2) {
  constexpr int K4 = K / 4;
  constexpr int LROW = K + 8;   // pad 8 bf16 (16 B) to break fragment-read bank conflicts
  __shared__ unsigned short sxb[64 * LROW];
  const int t = threadIdx.x;
  const int nb = blockIdx.x * 64;
  // stage x (fp32) -> LDS bf16, coalesced float4 reads
#pragma unroll
  for (int idx = t; idx < 64 * K4; idx += 256) {
    int node = idx / K4, k4 = idx - node * K4;
    float4 v = x4[(size_t)(nb + node) * K4 + k4];
    ushort4 h;
    h.x = f2bf(v.x); h.y = f2bf(v.y); h.z = f2bf(v.z); h.w = f2bf(v.w);
    *(ushort4*)&sxb[node * LROW + k4 * 4] = h;
  }
  __syncthreads();
  const int lane = t & 63;
  const int wv = t >> 6;
  const int col = lane & 15;
  const int quad = lane >> 4;
  f32x4v acc1[4], acc2[4];
#pragma unroll
  for (int ct = 0; ct < 4; ct++) {
    acc1[ct] = (f32x4v){0.f, 0.f, 0.f, 0.f};
    if (DUAL) {
      float bj = bias2[ct * 16 + col];
      acc2[ct] = (f32x4v){bj, bj, bj, bj};
    }
  }
#pragma unroll
  for (int s = 0; s < K / 32; s++) {
    bf16x8 a = *(const bf16x8*)&sxb[(wv * 16 + col) * LROW + s * 32 + quad * 8];
#pragma unroll
    for (int ct = 0; ct < 4; ct++) {
      bf16x8 b1 = *(const bf16x8*)&wb1[(size_t)((s * 4 + ct) * 64 + lane) * 8];
      acc1[ct] = __builtin_amdgcn_mfma_f32_16x16x32_bf16(a, b1, acc1[ct], 0, 0, 0);
      if (DUAL) {
        bf16x8 b2 = *(const bf16x8*)&wb2[(size_t)((s * 4 + ct) * 64 + lane) * 8];
        acc2[ct] = __builtin_amdgcn_mfma_f32_16x16x32_bf16(a, b2, acc2[ct], 0, 0, 0);
      }
    }
  }
#pragma unroll
  for (int ct = 0; ct < 4; ct++) {
#pragma unroll
    for (int reg = 0; reg < 4; reg++) {
      int node = nb + wv * 16 + quad * 4 + reg;
      unsigned pk = (unsigned)__builtin_amdgcn_cvt_pk_fp8_f32(acc1[ct][reg],
                                                              acc1[ct][reg], 0, false);
      out1[(size_t)node * 64 + ct * 16 + col] = (unsigned char)(pk & 0xff);
      if (DUAL) out2[(size_t)node * 64 + ct * 16 + col] = acc2[ct][reg];
    }
  }
}

// ---- gather aggregation over fp8 messages — reduction-free lane mapping ----
// lane = (node, quarter): 64 lanes = 16 nodes x 4 x 16-B quarters. Each lane
// serially sums its own 16-fp8 quarter over the node's edge list: NO cross-lane
// ops on the per-edge path. csr reads are linear (L1-hit); consecutive y-loads
// independent -> compiler pipelines several lines in flight per lane.
// Graph-mean partials: one all-lanes-active shfl tree per wave + LDS, written as
// deterministic per-block partials pm[graph][32][64] (no atomics).
template <int WRITE_H>
__global__ __launch_bounds__(256) void gather_k(const uint4* __restrict__ yb,
                                                const int* __restrict__ csr,
                                                const int* __restrict__ rowPtr,
                                                const float* __restrict__ invdeg,
                                                float4* __restrict__ hio,
                                                float* __restrict__ pm) {
  __shared__ float sg[4][4][16];
  const int t = threadIdx.x;
  const int lane = t & 63;
  const int wv = t >> 6;
  const int q = lane & 3;     // 16-B quarter of the 64-B row
  const int nl = lane >> 2;   // node within wave (0..15)
  const int nb = blockIdx.x * 64;   // 64 nodes per block (4 waves x 16)
  const int n = nb + wv * 16 + nl;
  const int rp0 = rowPtr[n], rp1 = rowPtr[n + 1];
  float acc[16];
#pragma unroll
  for (int k = 0; k < 16; k++) acc[k] = 0.f;
  for (int e = rp0; e < rp1; e++) {
    int s = csr[e];
    uint4 v = yb[(size_t)s * 4 + q];
    f32x2 p;
    p = __builtin_amdgcn_cvt_pk_f32_fp8(v.x, false); acc[0] += p.x;  acc[1] += p.y;
    p = __builtin_amdgcn_cvt_pk_f32_fp8(v.x, true);  acc[2] += p.x;  acc[3] += p.y;
    p = __builtin_amdgcn_cvt_pk_f32_fp8(v.y, false); acc[4] += p.x;  acc[5] += p.y;
    p = __builtin_amdgcn_cvt_pk_f32_fp8(v.y, true);  acc[6] += p.x;  acc[7] += p.y;
    p = __builtin_amdgcn_cvt_pk_f32_fp8(v.z, false); acc[8] += p.x;  acc[9] += p.y;
    p = __builtin_amdgcn_cvt_pk_f32_fp8(v.z, true);  acc[10] += p.x; acc[11] += p.y;
    p = __builtin_amdgcn_cvt_pk_f32_fp8(v.w, false); acc[12] += p.x; acc[13] += p.y;
    p = __builtin_amdgcn_cvt_pk_f32_fp8(v.w, true);  acc[14] += p.x; acc[15] += p.y;
  }
  const float sc = invdeg[n];
  float gacc[16];
  if (WRITE_H) {
#pragma unroll
    for (int u = 0; u < 4; u++) {
      float4 o = hio[(size_t)n * 16 + q * 4 + u];
      float4 h = make_float4(acc[4 * u + 0] * sc + o.x, acc[4 * u + 1] * sc + o.y,
                             acc[4 * u + 2] * sc + o.z, acc[4 * u + 3] * sc + o.w);
      hio[(size_t)n * 16 + q * 4 + u] = h;
      gacc[4 * u + 0] = h.x; gacc[4 * u + 1] = h.y;
      gacc[4 * u + 2] = h.z; gacc[4 * u + 3] = h.w;
    }
  } else {
#pragma unroll
    for (int k = 0; k < 16; k++) gacc[k] = acc[k] * sc;
  }
  // reduce across the wave's 16 nodes (lane bits 2..5) — ALL lanes active, uniform
#pragma unroll
  for (int m = 4; m <= 32; m <<= 1)
#pragma unroll
    for (int k = 0; k < 16; k++) gacc[k] += __shfl_xor(gacc[k], m, 64);
  if (nl == 0) {   // lanes 0..3 hold quarter q's wave sum
#pragma unroll
    for (int k = 0; k < 16; k++) sg[wv][q][k] = gacc[k];
  }
  __syncthreads();
  if (t < 64) {   // element j = t
    int qq = t >> 4, k = t & 15;
    float tot = sg[0][qq][k] + sg[1][qq][k] + sg[2][qq][k] + sg[3][qq][k];
    pm[((size_t)(blockIdx.x >> 5) * 32 + (blockIdx.x & 31)) * 64 + t] = tot;
  }
}

// ---- deterministic partial reduce: gm[b][j] = (1/2048) * sum_blk pm[b][blk][j] ----
__global__ __launch_bounds__(256) void reduce_part_k(const float* __restrict__ pm,
                                                     float* __restrict__ gm) {
  int idx = blockIdx.x * 256 + threadIdx.x;   // 4096
  int b = idx >> 6, j = idx & 63;
  float acc = 0.0f;
  for (int blk = 0; blk < 32; blk++) acc += pm[((size_t)b * 32 + blk) * 64 + j];
  gm[idx] = acc * (1.0f / 2048.0f);
}

// ---- g[b][j] = gmean2[b][j] + b2l[j] + sum_k gmean1[b][k] * W2r[j][k] ----
__global__ __launch_bounds__(256) void combine_k(const float* __restrict__ gmean2,
                                                 const float* __restrict__ gmean1,
                                                 const float* __restrict__ b2l,
                                                 const float* __restrict__ W2r,
                                                 float* __restrict__ g) {
  int idx = blockIdx.x * 256 + threadIdx.x;   // 4096
  int b = idx >> 6, j = idx & 63;
  const float4* m4 = (const float4*)(gmean1 + b * 64);
  const float4* w4 = (const float4*)(W2r + j * 64);
  float acc = gmean2[idx] + b2l[j];
#pragma unroll
  for (int k4 = 0; k4 < 16; k4++) {
    float4 mv = m4[k4], wv = w4[k4];
    acc += mv.x * wv.x + mv.y * wv.y + mv.z * wv.z + mv.w * wv.w;
  }
  g[idx] = acc;
}

// ---- h = relu(g @ fc1_W.T + fc1_b)   g:[64,64] fc1_W:[128,64] -> h:[64,128] ----
__global__ __launch_bounds__(256) void mlp1_k(const float* __restrict__ g,
                                              const float* __restrict__ fc1_W,
                                              const float* __restrict__ fc1_b,
                                              float* __restrict__ h) {
  int idx = blockIdx.x * 256 + threadIdx.x;
  int b = idx >> 7, k = idx & 127;
  const float4* g4 = (const float4*)(g + b * 64);
  const float4* w4 = (const float4*)(fc1_W + k * 64);
  float acc = fc1_b[k];
#pragma unroll
  for (int j4 = 0; j4 < 16; j4++) {
    float4 gv = g4[j4], wv = w4[j4];
    acc += gv.x * wv.x + gv.y * wv.y + gv.z * wv.z + gv.w * wv.w;
  }
  h[idx] = fmaxf(acc, 0.0f);
}

// ---- q = h @ fc2_W.T + fc2_b   h:[64,128] fc2_W:[2048,128] -> q:[64,2048] ----
__global__ __launch_bounds__(256) void mlp2_k(const float* __restrict__ h,
                                              const float* __restrict__ fc2_W,
                                              const float* __restrict__ fc2_b,
                                              float* __restrict__ out) {
  __shared__ float4 sh[32];
  int b = blockIdx.x >> 3;
  int a = (blockIdx.x & 7) * 256 + threadIdx.x;
  if (threadIdx.x < 32) sh[threadIdx.x] = ((const float4*)(h + b * 128))[threadIdx.x];
  __syncthreads();
  const float4* w4 = (const float4*)(fc2_W + (size_t)a * 128);
  float acc = fc2_b[a];
#pragma unroll
  for (int k4 = 0; k4 < 32; k4++) {
    float4 hv = sh[k4], wv = w4[k4];
    acc += hv.x * wv.x + hv.y * wv.y + hv.z * wv.z + hv.w * wv.w;
  }
  out[b * 2048 + a] = acc;
}

extern "C" void kernel_launch(void* const* d_in, const int* in_sizes, int n_in,
                              void* d_out, int out_size, void* d_ws, size_t ws_size,
                              hipStream_t stream) {
  const float* x     = (const float*)d_in[0];
  const int*   ei    = (const int*)d_in[1];
  const float* W1l   = (const float*)d_in[2];
  const float* b1l   = (const float*)d_in[3];
  const float* W1r   = (const float*)d_in[4];
  const float* W2l   = (const float*)d_in[5];
  const float* b2l   = (const float*)d_in[6];
  const float* W2r   = (const float*)d_in[7];
  const float* fc1_W = (const float*)d_in[8];
  const float* fc1_b = (const float*)d_in[9];
  const float* fc2_W = (const float*)d_in[10];
  const float* fc2_b = (const float*)d_in[11];
  float* out = (float*)d_out;

  const int N = in_sizes[0] / D_IN;   // 131072
  const int E = in_sizes[1] / 2;      // 2097152
  const int* src = ei;
  const int* dst = ei + E;

  // workspace layout (~59 MiB; 78 MiB proven available in round 3)
  char* ws = (char*)d_ws;
  int*   deg    = (int*)ws;     ws += (size_t)N * 4;
  int*   rowPtr = (int*)ws;     ws += (size_t)(N + 256) * 4;
  int*   bsum   = (int*)ws;     ws += 512 * 4;
  float* invdeg = (float*)ws;   ws += (size_t)N * 4;
  float* gmean1 = (float*)ws;   ws += 4096 * 4;
  float* gmean2 = (float*)ws;   ws += 4096 * 4;
  float* g      = (float*)ws;   ws += 4096 * 4;
  float* hbuf   = (float*)ws;   ws += 8192 * 4;
  unsigned short* wb1l = (unsigned short*)ws;  ws += 8192 * 2;  // mfma-packed bf16
  unsigned short* wb1r = (unsigned short*)ws;  ws += 8192 * 2;
  unsigned short* wb2l = (unsigned short*)ws;  ws += 4096 * 2;
  int*   bh     = (int*)ws;     ws += 8192 * 4;   // transposed per-block bucket hist
  int*   bbase  = (int*)ws;     ws += 16 * 4;     // bucket starts [9]
  float* p1     = (float*)ws;   ws += (size_t)64 * 32 * 64 * 4;  // graph-mean partials
  float* p2     = (float*)ws;   ws += (size_t)64 * 32 * 64 * 4;
  unsigned int* bkt = (unsigned int*)ws;  ws += (size_t)E * 4;   // packed edge buckets
  int*   csr    = (int*)ws;     ws += (size_t)E * 4;
  unsigned char* bufA = (unsigned char*)ws;  ws += (size_t)64 * N;      // y1/y2 fp8
  float* bufB   = (float*)ws;   ws += (size_t)64 * N * 4;  // xr -> h1 (in place, fp32)
  size_t used = (size_t)(ws - (char*)d_ws);

  // Zero the ENTIRE used workspace every call (round-10 fix: every call must
  // start from the identical, validated-benign state; ~10 us at HBM write BW).
  hipMemsetAsync(d_ws, 0, used, stream);

  wprep_mfma_k<<<4, 256, 0, stream>>>(W1l, wb1l, 128);
  wprep_mfma_k<<<4, 256, 0, stream>>>(W1r, wb1r, 128);
  wprep_mfma_k<<<2, 256, 0, stream>>>(W2l, wb2l, 64);

  // CSR build (round-12): 8-way XCD bucketing, then per-sub LDS counting sort.
  // No scattered global stores anywhere: deg and csr are written coalesced.
  bhist_k<<<1024, 256, 0, stream>>>(dst, bh, E);
  bscan_k<<<1, 256, 0, stream>>>(bh, bbase);
  bfill_k<<<1024, 256, 0, stream>>>(src, dst, bh, bkt, E);
  deg3_k<<<256, 256, 0, stream>>>(bkt, bbase, deg, N);
  blocksum_k<<<N / 256, 256, 0, stream>>>(deg, bsum);
  scanbsum_k<<<1, 256, 0, stream>>>(bsum);
  rowptr_k<<<N / 256, 256, 0, stream>>>(deg, bsum, rowPtr, invdeg);
  scat3_k<<<256, 256, 0, stream>>>(bkt, bbase, rowPtr, csr, N);

  // conv1: y1 = fp8(x@W1l.T) -> bufA ; xr = b1l + x@W1r.T -> bufB (fp32)
  gemm_mfma_k<128, 1><<<N / 64, 256, 0, stream>>>((const float4*)x, wb1l, wb1r,
                                                  b1l, bufA, bufB);
  // h1 = gather(y1)*invdeg + xr -> bufB in place; p1 partials
  gather_k<1><<<N / 64, 256, 0, stream>>>((const uint4*)bufA, csr, rowPtr, invdeg,
                                          (float4*)bufB, p1);
  reduce_part_k<<<16, 256, 0, stream>>>(p1, gmean1);

  // conv2: y2 = fp8(h1@W2l.T) -> bufA
  gemm_mfma_k<64, 0><<<N / 64, 256, 0, stream>>>((const float4*)bufB, wb2l, nullptr,
                                                 nullptr, bufA, nullptr);
  // p2 partials of gather(y2)*invdeg  (h2 never materialized)
  gather_k<0><<<N / 64, 256, 0, stream>>>((const uint4*)bufA, csr, rowPtr, invdeg,
                                          nullptr, p2);
  reduce_part_k<<<16, 256, 0, stream>>>(p2, gmean2);

  // g = gmean2 + b2l + gmean1 @ W2r.T
  combine_k<<<16, 256, 0, stream>>>(gmean2, gmean1, b2l, W2r, g);
  mlp1_k<<<32, 256, 0, stream>>>(g, fc1_W, fc1_b, hbuf);
  mlp2_k<<<512, 256, 0, stream>>>(hbuf, fc2_W, fc2_b, out);
}

// Round 5
// 355.557 us; speedup vs baseline: 2.1562x; 2.1562x over previous
//
#include <hip/hip_runtime.h>
#include <hip/hip_bf16.h>

#define D_IN 128
#define D_EMB 64

typedef float f32x2 __attribute__((ext_vector_type(2)));
typedef float f32x4v __attribute__((ext_vector_type(4)));
typedef short bf16x8 __attribute__((ext_vector_type(8)));   // 8 bf16 = 4 VGPRs (guide §3)

static __device__ __forceinline__ unsigned short f2bf(float f) {
  __hip_bfloat16 h = __float2bfloat16(f);
  return *(unsigned short*)&h;
}

// ---- MFMA weight prep: W[64][K] fp32 -> packed bf16 B-fragments.
// frag index tid=(s*4+ct)*64+lane holds W[ct*16+(lane&15)][s*32+(lane>>4)*8 + j], j=0..7
__global__ __launch_bounds__(256) void wprep_mfma_k(const float* __restrict__ W,
                                                    unsigned short* __restrict__ out,
                                                    int K) {
  int tid = blockIdx.x * 256 + threadIdx.x;
  int total = (K / 32) * 4 * 64;
  if (tid >= total) return;
  int lane = tid & 63;
  int ct = (tid >> 6) & 3;
  int s = tid >> 8;
  int row = ct * 16 + (lane & 15);
  int kk = s * 32 + (lane >> 4) * 8;
  unsigned short tmp[8];
#pragma unroll
  for (int j = 0; j < 8; j++) tmp[j] = f2bf(W[row * K + kk + j]);
  *(uint4*)&out[(size_t)tid * 8] = *(uint4*)tmp;
}

// ==== CSR build, round-16: single-pass 256-way sub-bucket sort ====
// Round-4 post-mortem: LDS scatter + coalesced flush fixed WRITE_SIZE (8.2MB
// = payload, theory confirmed) but scan-and-filter (each block scanning its
// whole 1MB partition for the 1/32 it owns = 1024 load iters at 1 block/CU)
// was latency death: 286us at 0.56% HBM, 11.6% occupancy. Fix: bin edges
// directly into 256 node-order sub-buckets (512 nodes each) so deg/scat read
// ONLY their own ~8192-entry contiguous range (32 iters). The binning pass
// avoids partial-line global scatters (round-11 evidence: ~46B HBM write per
// 4B scattered store) by counting-sorting each 2048-edge chunk in LDS first,
// then writing out linearly: consecutive lanes -> consecutive addresses.

// Per-chunk 256-bin histogram of dst>>9, written TRANSPOSED bh[bin*1024+chunk].
// bh rows are 1024 chunks; unused chunks stay 0 from the workspace memset.
__global__ __launch_bounds__(256) void bhist1_k(const int* __restrict__ dst,
                                                int* __restrict__ bh, int E) {
  __shared__ int h[256];
  const int t = threadIdx.x;
  h[t] = 0;
  __syncthreads();
  const int base = blockIdx.x * 2048;
#pragma unroll
  for (int j = 0; j < 8; j++) {
    int e = base + j * 256 + t;
    if (e < E) atomicAdd(&h[dst[e] >> 9], 1);
  }
  __syncthreads();
  bh[t * 1024 + blockIdx.x] = h[t];
}

// Per-bin exclusive scan over the 1024 chunks (one block per bin), in place.
// Emits bintot[bin].
__global__ __launch_bounds__(256) void scanA_k(int* __restrict__ bh,
                                               int* __restrict__ bintot) {
  __shared__ int sa[256], sb[256];
  const int t = threadIdx.x;
  int* row = bh + (size_t)blockIdx.x * 1024;
  int v0 = row[t * 4], v1 = row[t * 4 + 1], v2 = row[t * 4 + 2], v3 = row[t * 4 + 3];
  int sum = v0 + v1 + v2 + v3;
  sa[t] = sum;
  __syncthreads();
  int* in = sa;
  int* out = sb;
  for (int st = 1; st < 256; st <<= 1) {
    out[t] = in[t] + (t >= st ? in[t - st] : 0);
    __syncthreads();
    int* tmp = in; in = out; out = tmp;
  }
  int excl = in[t] - sum;
  row[t * 4] = excl;
  row[t * 4 + 1] = excl + v0;
  row[t * 4 + 2] = excl + v0 + v1;
  row[t * 4 + 3] = excl + v0 + v1 + v2;
  if (t == 255) bintot[blockIdx.x] = in[255];
}

// Exclusive scan of the 256 bin totals -> sbase[256] sub-bucket starts,
// sbase[256]=E.
__global__ __launch_bounds__(256) void scanB_k(const int* __restrict__ bintot,
                                               int* __restrict__ sbase) {
  __shared__ int sa[256], sb[256];
  const int t = threadIdx.x;
  int v = bintot[t];
  sa[t] = v;
  __syncthreads();
  int* in = sa;
  int* out = sb;
  for (int st = 1; st < 256; st <<= 1) {
    out[t] = in[t] + (t >= st ? in[t - st] : 0);
    __syncthreads();
    int* tmp = in; in = out; out = tmp;
  }
  sbase[t] = in[t] - v;
  if (t == 255) sbase[256] = in[255];
}

// LDS chunk-sort binning: hist -> scan -> LDS counting scatter -> linear
// write-out. Global stores are coalesced runs (consecutive lanes, consecutive
// addresses within each bin run) -> line-dominated writes, no scatter amp.
// Packed word: (dst&511)<<17 | src  (9b node-in-sub + 17b src, N=2^17).
__global__ __launch_bounds__(256) void bfill1_k(const int* __restrict__ src,
                                                const int* __restrict__ dst,
                                                const int* __restrict__ bh,
                                                const int* __restrict__ sbase,
                                                unsigned int* __restrict__ bkt,
                                                int E) {
  __shared__ int hA[256], hB[256], runCur[256], gb[256];
  __shared__ int dcache[2048];
  __shared__ unsigned int sorted[2048];
  __shared__ unsigned short subb[2048];
  const int t = threadIdx.x;
  const int base = blockIdx.x * 2048;
  const int n = min(2048, E - base);
  hA[t] = 0;
  __syncthreads();
  // phase 1: hist + dst cache
#pragma unroll
  for (int j = 0; j < 8; j++) {
    int idx = j * 256 + t;
    int e = base + idx;
    if (idx < n) {
      int d = dst[e];
      dcache[idx] = d;
      atomicAdd(&hA[d >> 9], 1);
    }
  }
  __syncthreads();
  // phase 2: exclusive scan of hist (ping-pong; 8 steps -> result back in hA)
  int cnt = hA[t];
  int* in = hA;
  int* out = hB;
  for (int st = 1; st < 256; st <<= 1) {
    out[t] = in[t] + (t >= st ? in[t - st] : 0);
    __syncthreads();
    int* tmp = in; in = out; out = tmp;
  }
  int rs = in[t] - cnt;   // exclusive prefix = chunk-local run start of bin t
  __syncthreads();
  hB[t] = rs;             // stable runStart
  runCur[t] = rs;
  gb[t] = sbase[t] + bh[t * 1024 + blockIdx.x];   // global base of (bin t, this chunk)
  __syncthreads();
  // phase 3: LDS counting scatter
#pragma unroll
  for (int j = 0; j < 8; j++) {
    int idx = j * 256 + t;
    int e = base + idx;
    if (idx < n) {
      int d = dcache[idx];
      int b = d >> 9;
      int lpos = atomicAdd(&runCur[b], 1);
      sorted[lpos] = ((unsigned)(d & 511) << 17) | (unsigned)src[e];
      subb[lpos] = (unsigned short)b;
    }
  }
  __syncthreads();
  // phase 4: linear write-out (coalesced within runs)
  for (int idx = t; idx < n; idx += 256) {
    int b = subb[idx];
    bkt[gb[b] + idx - hB[b]] = sorted[idx];
  }
}

// Per-sub degree count: block i reads ONLY its own contiguous sub-bucket
// (~8192 entries, 32 iters), LDS histogram, coalesced atomic-free deg write.
__global__ __launch_bounds__(256) void deg4_k(const unsigned int* __restrict__ bkt,
                                              const int* __restrict__ sbase,
                                              int* __restrict__ deg) {
  __shared__ int h[512];
  const int t = threadIdx.x;
  h[t] = 0;
  h[t + 256] = 0;
  __syncthreads();
  const int i = blockIdx.x;
  const int lo = sbase[i], hi = sbase[i + 1];
  for (int e = lo + t; e < hi; e += 256) atomicAdd(&h[bkt[e] >> 17], 1);
  __syncthreads();
  deg[i * 512 + t] = h[t];
  deg[i * 512 + t + 256] = h[t + 256];
}

__global__ __launch_bounds__(256) void blocksum_k(const int* __restrict__ deg,
                                                  int* __restrict__ bsum) {
  __shared__ int sm[256];
  int t = threadIdx.x;
  sm[t] = deg[blockIdx.x * 256 + t];
  __syncthreads();
  for (int s = 128; s > 0; s >>= 1) {
    if (t < s) sm[t] += sm[t + s];
    __syncthreads();
  }
  if (t == 0) bsum[blockIdx.x] = sm[0];
}

// single block: exclusive scan of 512 block sums (in place)
__global__ __launch_bounds__(256) void scanbsum_k(int* __restrict__ bsum) {
  __shared__ int a[512], b[512];
  int t = threadIdx.x;
  a[t] = bsum[t];
  a[t + 256] = bsum[t + 256];
  __syncthreads();
  int* in = a;
  int* out = b;
  for (int st = 1; st < 512; st <<= 1) {
    for (int i = t; i < 512; i += 256) out[i] = in[i] + (i >= st ? in[i - st] : 0);
    __syncthreads();
    int* tmp = in; in = out; out = tmp;
  }
  for (int i = t; i < 512; i += 256) bsum[i] = (i == 0) ? 0 : in[i - 1];
}

// per-block inclusive scan of deg + block offset -> rowPtr (exclusive), fused invdeg
__global__ __launch_bounds__(256) void rowptr_k(const int* __restrict__ deg,
                                                const int* __restrict__ bsumEx,
                                                int* __restrict__ rowPtr,
                                                float* __restrict__ invdeg) {
  __shared__ int a[256], b[256];
  int t = threadIdx.x;
  int i = blockIdx.x * 256 + t;
  int d = deg[i];
  a[t] = d;
  __syncthreads();
  int* in = a;
  int* out = b;
  for (int st = 1; st < 256; st <<= 1) {
    out[t] = in[t] + (t >= st ? in[t - st] : 0);
    __syncthreads();
    int* tmp = in; in = out; out = tmp;
  }
  int incl = in[t] + bsumEx[blockIdx.x];
  rowPtr[i + 1] = incl;
  invdeg[i] = 1.0f / fmaxf((float)d, 1.0f);
  if (i == 0) rowPtr[0] = 0;
}

// Per-sub LDS counting scatter (proven WRITE_SIZE ~= payload in round 4),
// now reading ONLY its own sub-bucket: 32 iters instead of 1024.
#define CSR_CAP 12032
__global__ __launch_bounds__(256) void scat4_k(const unsigned int* __restrict__ bkt,
                                               const int* __restrict__ sbase,
                                               const int* __restrict__ rowPtr,
                                               int* __restrict__ csr) {
  __shared__ int cur[512];
  __shared__ int cbuf[CSR_CAP];
  const int t = threadIdx.x;
  const int i = blockIdx.x;
  const int node0 = i * 512;
  const int base0 = rowPtr[node0];
  cur[t] = rowPtr[node0 + t] - base0;
  cur[t + 256] = rowPtr[node0 + t + 256] - base0;
  __syncthreads();
  const int lo = sbase[i], hi = sbase[i + 1];
  for (int e = lo + t; e < hi; e += 256) {
    unsigned v = bkt[e];
    int pos = atomicAdd(&cur[v >> 17], 1);
    int sval = (int)(v & 0x1FFFFu);
    if (pos < CSR_CAP) cbuf[pos] = sval;
    else csr[base0 + pos] = sval;   // never taken for uniform-random input
  }
  __syncthreads();
  const int cnt = rowPtr[node0 + 512] - base0;
  const int lim = cnt < CSR_CAP ? cnt : CSR_CAP;
  for (int idx = t; idx < lim; idx += 256) csr[base0 + idx] = cbuf[idx];
}

// ---- MFMA GEMM: 64 nodes/block, 4 waves x 16-node tile, 16x16x32 bf16 MFMA.
// out1 = fp8_e4m3(x @ W1.T) ; DUAL: out2 = fp32(bias2 + x @ W2.T)
// A-frag: A[m=lane&15][k=quad*8+j] (guide-verified). B pre-packed by wprep_mfma_k.
// C/D: col=lane&15, row=quad*4+reg (m89-verified).
template <int K, int DUAL>
__global__ __launch_bounds__(256) void gemm_mfma_k(const float4* __restrict__ x4,
                                                   const unsigned short* __restrict__ wb1,
                                                   const unsigned short* __restrict__ wb2,
                                                   const float* __restrict__ bias2,
                                                   unsigned char* __restrict__ out1,
                                                   float* __restrict__ out2) {
  constexpr int K4 = K / 4;
  constexpr int LROW = K + 8;   // pad 8 bf16 (16 B) to break fragment-read bank conflicts
  __shared__ unsigned short sxb[64 * LROW];
  const int t = threadIdx.x;
  const int nb = blockIdx.x * 64;
  // stage x (fp32) -> LDS bf16, coalesced float4 reads
#pragma unroll
  for (int idx = t; idx < 64 * K4; idx += 256) {
    int node = idx / K4, k4 = idx - node * K4;
    float4 v = x4[(size_t)(nb + node) * K4 + k4];
    ushort4 h;
    h.x = f2bf(v.x); h.y = f2bf(v.y); h.z = f2bf(v.z); h.w = f2bf(v.w);
    *(ushort4*)&sxb[node * LROW + k4 * 4] = h;
  }
  __syncthreads();
  const int lane = t & 63;
  const int wv = t >> 6;
  const int col = lane & 15;
  const int quad = lane >> 4;
  f32x4v acc1[4], acc2[4];
#pragma unroll
  for (int ct = 0; ct < 4; ct++) {
    acc1[ct] = (f32x4v){0.f, 0.f, 0.f, 0.f};
    if (DUAL) {
      float bj = bias2[ct * 16 + col];
      acc2[ct] = (f32x4v){bj, bj, bj, bj};
    }
  }
#pragma unroll
  for (int s = 0; s < K / 32; s++) {
    bf16x8 a = *(const bf16x8*)&sxb[(wv * 16 + col) * LROW + s * 32 + quad * 8];
#pragma unroll
    for (int ct = 0; ct < 4; ct++) {
      bf16x8 b1 = *(const bf16x8*)&wb1[(size_t)((s * 4 + ct) * 64 + lane) * 8];
      acc1[ct] = __builtin_amdgcn_mfma_f32_16x16x32_bf16(a, b1, acc1[ct], 0, 0, 0);
      if (DUAL) {
        bf16x8 b2 = *(const bf16x8*)&wb2[(size_t)((s * 4 + ct) * 64 + lane) * 8];
        acc2[ct] = __builtin_amdgcn_mfma_f32_16x16x32_bf16(a, b2, acc2[ct], 0, 0, 0);
      }
    }
  }
#pragma unroll
  for (int ct = 0; ct < 4; ct++) {
#pragma unroll
    for (int reg = 0; reg < 4; reg++) {
      int node = nb + wv * 16 + quad * 4 + reg;
      unsigned pk = (unsigned)__builtin_amdgcn_cvt_pk_fp8_f32(acc1[ct][reg],
                                                              acc1[ct][reg], 0, false);
      out1[(size_t)node * 64 + ct * 16 + col] = (unsigned char)(pk & 0xff);
      if (DUAL) out2[(size_t)node * 64 + ct * 16 + col] = acc2[ct][reg];
    }
  }
}

// ---- gather aggregation over fp8 messages — reduction-free lane mapping ----
// lane = (node, quarter): 64 lanes = 16 nodes x 4 x 16-B quarters. Each lane
// serially sums its own 16-fp8 quarter over the node's edge list: NO cross-lane
// ops on the per-edge path. csr reads are linear (L1-hit); consecutive y-loads
// independent -> compiler pipelines several lines in flight per lane.
// Graph-mean partials: one all-lanes-active shfl tree per wave + LDS, written as
// deterministic per-block partials pm[graph][32][64] (no atomics).
template <int WRITE_H>
__global__ __launch_bounds__(256) void gather_k(const uint4* __restrict__ yb,
                                                const int* __restrict__ csr,
                                                const int* __restrict__ rowPtr,
                                                const float* __restrict__ invdeg,
                                                float4* __restrict__ hio,
                                                float* __restrict__ pm) {
  __shared__ float sg[4][4][16];
  const int t = threadIdx.x;
  const int lane = t & 63;
  const int wv = t >> 6;
  const int q = lane & 3;     // 16-B quarter of the 64-B row
  const int nl = lane >> 2;   // node within wave (0..15)
  const int nb = blockIdx.x * 64;   // 64 nodes per block (4 waves x 16)
  const int n = nb + wv * 16 + nl;
  const int rp0 = rowPtr[n], rp1 = rowPtr[n + 1];
  float acc[16];
#pragma unroll
  for (int k = 0; k < 16; k++) acc[k] = 0.f;
  for (int e = rp0; e < rp1; e++) {
    int s = csr[e];
    uint4 v = yb[(size_t)s * 4 + q];
    f32x2 p;
    p = __builtin_amdgcn_cvt_pk_f32_fp8(v.x, false); acc[0] += p.x;  acc[1] += p.y;
    p = __builtin_amdgcn_cvt_pk_f32_fp8(v.x, true);  acc[2] += p.x;  acc[3] += p.y;
    p = __builtin_amdgcn_cvt_pk_f32_fp8(v.y, false); acc[4] += p.x;  acc[5] += p.y;
    p = __builtin_amdgcn_cvt_pk_f32_fp8(v.y, true);  acc[6] += p.x;  acc[7] += p.y;
    p = __builtin_amdgcn_cvt_pk_f32_fp8(v.z, false); acc[8] += p.x;  acc[9] += p.y;
    p = __builtin_amdgcn_cvt_pk_f32_fp8(v.z, true);  acc[10] += p.x; acc[11] += p.y;
    p = __builtin_amdgcn_cvt_pk_f32_fp8(v.w, false); acc[12] += p.x; acc[13] += p.y;
    p = __builtin_amdgcn_cvt_pk_f32_fp8(v.w, true);  acc[14] += p.x; acc[15] += p.y;
  }
  const float sc = invdeg[n];
  float gacc[16];
  if (WRITE_H) {
#pragma unroll
    for (int u = 0; u < 4; u++) {
      float4 o = hio[(size_t)n * 16 + q * 4 + u];
      float4 h = make_float4(acc[4 * u + 0] * sc + o.x, acc[4 * u + 1] * sc + o.y,
                             acc[4 * u + 2] * sc + o.z, acc[4 * u + 3] * sc + o.w);
      hio[(size_t)n * 16 + q * 4 + u] = h;
      gacc[4 * u + 0] = h.x; gacc[4 * u + 1] = h.y;
      gacc[4 * u + 2] = h.z; gacc[4 * u + 3] = h.w;
    }
  } else {
#pragma unroll
    for (int k = 0; k < 16; k++) gacc[k] = acc[k] * sc;
  }
  // reduce across the wave's 16 nodes (lane bits 2..5) — ALL lanes active, uniform
#pragma unroll
  for (int m = 4; m <= 32; m <<= 1)
#pragma unroll
    for (int k = 0; k < 16; k++) gacc[k] += __shfl_xor(gacc[k], m, 64);
  if (nl == 0) {   // lanes 0..3 hold quarter q's wave sum
#pragma unroll
    for (int k = 0; k < 16; k++) sg[wv][q][k] = gacc[k];
  }
  __syncthreads();
  if (t < 64) {   // element j = t
    int qq = t >> 4, k = t & 15;
    float tot = sg[0][qq][k] + sg[1][qq][k] + sg[2][qq][k] + sg[3][qq][k];
    pm[((size_t)(blockIdx.x >> 5) * 32 + (blockIdx.x & 31)) * 64 + t] = tot;
  }
}

// ---- deterministic partial reduce: gm[b][j] = (1/2048) * sum_blk pm[b][blk][j] ----
__global__ __launch_bounds__(256) void reduce_part_k(const float* __restrict__ pm,
                                                     float* __restrict__ gm) {
  int idx = blockIdx.x * 256 + threadIdx.x;   // 4096
  int b = idx >> 6, j = idx & 63;
  float acc = 0.0f;
  for (int blk = 0; blk < 32; blk++) acc += pm[((size_t)b * 32 + blk) * 64 + j];
  gm[idx] = acc * (1.0f / 2048.0f);
}

// ---- g[b][j] = gmean2[b][j] + b2l[j] + sum_k gmean1[b][k] * W2r[j][k] ----
__global__ __launch_bounds__(256) void combine_k(const float* __restrict__ gmean2,
                                                 const float* __restrict__ gmean1,
                                                 const float* __restrict__ b2l,
                                                 const float* __restrict__ W2r,
                                                 float* __restrict__ g) {
  int idx = blockIdx.x * 256 + threadIdx.x;   // 4096
  int b = idx >> 6, j = idx & 63;
  const float4* m4 = (const float4*)(gmean1 + b * 64);
  const float4* w4 = (const float4*)(W2r + j * 64);
  float acc = gmean2[idx] + b2l[j];
#pragma unroll
  for (int k4 = 0; k4 < 16; k4++) {
    float4 mv = m4[k4], wv = w4[k4];
    acc += mv.x * wv.x + mv.y * wv.y + mv.z * wv.z + mv.w * wv.w;
  }
  g[idx] = acc;
}

// ---- h = relu(g @ fc1_W.T + fc1_b)   g:[64,64] fc1_W:[128,64] -> h:[64,128] ----
__global__ __launch_bounds__(256) void mlp1_k(const float* __restrict__ g,
                                              const float* __restrict__ fc1_W,
                                              const float* __restrict__ fc1_b,
                                              float* __restrict__ h) {
  int idx = blockIdx.x * 256 + threadIdx.x;
  int b = idx >> 7, k = idx & 127;
  const float4* g4 = (const float4*)(g + b * 64);
  const float4* w4 = (const float4*)(fc1_W + k * 64);
  float acc = fc1_b[k];
#pragma unroll
  for (int j4 = 0; j4 < 16; j4++) {
    float4 gv = g4[j4], wv = w4[j4];
    acc += gv.x * wv.x + gv.y * wv.y + gv.z * wv.z + gv.w * wv.w;
  }
  h[idx] = fmaxf(acc, 0.0f);
}

// ---- q = h @ fc2_W.T + fc2_b   h:[64,128] fc2_W:[2048,128] -> q:[64,2048] ----
__global__ __launch_bounds__(256) void mlp2_k(const float* __restrict__ h,
                                              const float* __restrict__ fc2_W,
                                              const float* __restrict__ fc2_b,
                                              float* __restrict__ out) {
  __shared__ float4 sh[32];
  int b = blockIdx.x >> 3;
  int a = (blockIdx.x & 7) * 256 + threadIdx.x;
  if (threadIdx.x < 32) sh[threadIdx.x] = ((const float4*)(h + b * 128))[threadIdx.x];
  __syncthreads();
  const float4* w4 = (const float4*)(fc2_W + (size_t)a * 128);
  float acc = fc2_b[a];
#pragma unroll
  for (int k4 = 0; k4 < 32; k4++) {
    float4 hv = sh[k4], wv = w4[k4];
    acc += hv.x * wv.x + hv.y * wv.y + hv.z * wv.z + hv.w * wv.w;
  }
  out[b * 2048 + a] = acc;
}

extern "C" void kernel_launch(void* const* d_in, const int* in_sizes, int n_in,
                              void* d_out, int out_size, void* d_ws, size_t ws_size,
                              hipStream_t stream) {
  const float* x     = (const float*)d_in[0];
  const int*   ei    = (const int*)d_in[1];
  const float* W1l   = (const float*)d_in[2];
  const float* b1l   = (const float*)d_in[3];
  const float* W1r   = (const float*)d_in[4];
  const float* W2l   = (const float*)d_in[5];
  const float* b2l   = (const float*)d_in[6];
  const float* W2r   = (const float*)d_in[7];
  const float* fc1_W = (const float*)d_in[8];
  const float* fc1_b = (const float*)d_in[9];
  const float* fc2_W = (const float*)d_in[10];
  const float* fc2_b = (const float*)d_in[11];
  float* out = (float*)d_out;

  const int N = in_sizes[0] / D_IN;   // 131072
  const int E = in_sizes[1] / 2;      // 2097152
  const int* src = ei;
  const int* dst = ei + E;

  // workspace layout (~61 MiB; 78 MiB proven available)
  char* ws = (char*)d_ws;
  int*   deg    = (int*)ws;     ws += (size_t)N * 4;
  int*   rowPtr = (int*)ws;     ws += (size_t)(N + 256) * 4;
  int*   bsum   = (int*)ws;     ws += 512 * 4;
  float* invdeg = (float*)ws;   ws += (size_t)N * 4;
  float* gmean1 = (float*)ws;   ws += 4096 * 4;
  float* gmean2 = (float*)ws;   ws += 4096 * 4;
  float* g      = (float*)ws;   ws += 4096 * 4;
  float* hbuf   = (float*)ws;   ws += 8192 * 4;
  unsigned short* wb1l = (unsigned short*)ws;  ws += 8192 * 2;  // mfma-packed bf16
  unsigned short* wb1r = (unsigned short*)ws;  ws += 8192 * 2;
  unsigned short* wb2l = (unsigned short*)ws;  ws += 4096 * 2;
  int*   bh     = (int*)ws;     ws += (size_t)256 * 1024 * 4;  // [bin][chunk] hist/scan
  int*   bintot = (int*)ws;     ws += 256 * 4;
  int*   sbase  = (int*)ws;     ws += 260 * 4;    // sub-bucket starts [257]
  float* p1     = (float*)ws;   ws += (size_t)64 * 32 * 64 * 4;  // graph-mean partials
  float* p2     = (float*)ws;   ws += (size_t)64 * 32 * 64 * 4;
  unsigned int* bkt = (unsigned int*)ws;  ws += (size_t)E * 4;   // sub-binned edges
  int*   csr    = (int*)ws;     ws += (size_t)E * 4;
  unsigned char* bufA = (unsigned char*)ws;  ws += (size_t)64 * N;      // y1/y2 fp8
  float* bufB   = (float*)ws;   ws += (size_t)64 * N * 4;  // xr -> h1 (in place, fp32)
  size_t used = (size_t)(ws - (char*)d_ws);

  // Zero the ENTIRE used workspace every call (round-10 fix: every call must
  // start from the identical, validated-benign state; ~10 us at HBM write BW).
  hipMemsetAsync(d_ws, 0, used, stream);

  wprep_mfma_k<<<4, 256, 0, stream>>>(W1l, wb1l, 128);
  wprep_mfma_k<<<4, 256, 0, stream>>>(W1r, wb1r, 128);
  wprep_mfma_k<<<2, 256, 0, stream>>>(W2l, wb2l, 64);

  // CSR build (round-16): single-pass 256-way LDS chunk-sort binning, then
  // per-sub LDS histogram + counting scatter. No scattered global stores,
  // no scan-and-filter: every kernel reads/writes only what it owns.
  const int nch = (E + 2047) >> 11;   // 1024 for E=2M (bh rows sized 1024)
  bhist1_k<<<nch, 256, 0, stream>>>(dst, bh, E);
  scanA_k<<<256, 256, 0, stream>>>(bh, bintot);
  scanB_k<<<1, 256, 0, stream>>>(bintot, sbase);
  bfill1_k<<<nch, 256, 0, stream>>>(src, dst, bh, sbase, bkt, E);
  deg4_k<<<256, 256, 0, stream>>>(bkt, sbase, deg);
  blocksum_k<<<N / 256, 256, 0, stream>>>(deg, bsum);
  scanbsum_k<<<1, 256, 0, stream>>>(bsum);
  rowptr_k<<<N / 256, 256, 0, stream>>>(deg, bsum, rowPtr, invdeg);
  scat4_k<<<256, 256, 0, stream>>>(bkt, sbase, rowPtr, csr);

  // conv1: y1 = fp8(x@W1l.T) -> bufA ; xr = b1l + x@W1r.T -> bufB (fp32)
  gemm_mfma_k<128, 1><<<N / 64, 256, 0, stream>>>((const float4*)x, wb1l, wb1r,
                                                  b1l, bufA, bufB);
  // h1 = gather(y1)*invdeg + xr -> bufB in place; p1 partials
  gather_k<1><<<N / 64, 256, 0, stream>>>((const uint4*)bufA, csr, rowPtr, invdeg,
                                          (float4*)bufB, p1);
  reduce_part_k<<<16, 256, 0, stream>>>(p1, gmean1);

  // conv2: y2 = fp8(h1@W2l.T) -> bufA
  gemm_mfma_k<64, 0><<<N / 64, 256, 0, stream>>>((const float4*)bufB, wb2l, nullptr,
                                                 nullptr, bufA, nullptr);
  // p2 partials of gather(y2)*invdeg  (h2 never materialized)
  gather_k<0><<<N / 64, 256, 0, stream>>>((const uint4*)bufA, csr, rowPtr, invdeg,
                                          nullptr, p2);
  reduce_part_k<<<16, 256, 0, stream>>>(p2, gmean2);

  // g = gmean2 + b2l + gmean1 @ W2r.T
  combine_k<<<16, 256, 0, stream>>>(gmean2, gmean1, b2l, W2r, g);
  mlp1_k<<<32, 256, 0, stream>>>(g, fc1_W, fc1_b, hbuf);
  mlp2_k<<<512, 256, 0, stream>>>(hbuf, fc2_W, fc2_b, out);
}

// Round 6
// 355.158 us; speedup vs baseline: 2.1586x; 1.0011x over previous
//
#include <hip/hip_runtime.h>
#include <hip/hip_bf16.h>

#define D_IN 128
#define D_EMB 64

typedef float f32x2 __attribute__((ext_vector_type(2)));
typedef float f32x4v __attribute__((ext_vector_type(4)));
typedef short bf16x8 __attribute__((ext_vector_type(8)));   // 8 bf16 = 4 VGPRs (guide §3)

static __device__ __forceinline__ unsigned short f2bf(float f) {
  __hip_bfloat16 h = __float2bfloat16(f);
  return *(unsigned short*)&h;
}

// ---- MFMA weight prep: W[64][K] fp32 -> packed bf16 B-fragments.
// frag index tid=(s*4+ct)*64+lane holds W[ct*16+(lane&15)][s*32+(lane>>4)*8 + j], j=0..7
__global__ __launch_bounds__(256) void wprep_mfma_k(const float* __restrict__ W,
                                                    unsigned short* __restrict__ out,
                                                    int K) {
  int tid = blockIdx.x * 256 + threadIdx.x;
  int total = (K / 32) * 4 * 64;
  if (tid >= total) return;
  int lane = tid & 63;
  int ct = (tid >> 6) & 3;
  int s = tid >> 8;
  int row = ct * 16 + (lane & 15);
  int kk = s * 32 + (lane >> 4) * 8;
  unsigned short tmp[8];
#pragma unroll
  for (int j = 0; j < 8; j++) tmp[j] = f2bf(W[row * K + kk + j]);
  *(uint4*)&out[(size_t)tid * 8] = *(uint4*)tmp;
}

// ==== CSR build, round-17: src-sorted edge lists for gather L2 locality ====
// Round-5 evidence: gather_k FETCH 159MB (y-gather ~120MB for an 8MB buffer,
// HBM at 3.47TB/s = random-64B efficiency ceiling). Fix: src-sort each node's
// edge list so concurrent gather lanes sweep y coherently (order-statistic
// cohort ~ +-11% band => L2-resident). Pass 0: counting sort by src>>9
// (sfill_k -> srcS/dstS). Pass 1: existing dst-sub sort reading the sorted
// arrays (stable at chunk granularity -> per-node lists stay src-ordered).

// Per-chunk 256-bin histogram of key>>9, written TRANSPOSED h[bin*1024+chunk].
// Rows are 1024 chunks; unused chunks stay 0 from the workspace memset.
__global__ __launch_bounds__(256) void bhist1_k(const int* __restrict__ key,
                                                int* __restrict__ bh, int E) {
  __shared__ int h[256];
  const int t = threadIdx.x;
  h[t] = 0;
  __syncthreads();
  const int base = blockIdx.x * 2048;
#pragma unroll
  for (int j = 0; j < 8; j++) {
    int e = base + j * 256 + t;
    if (e < E) atomicAdd(&h[key[e] >> 9], 1);
  }
  __syncthreads();
  bh[t * 1024 + blockIdx.x] = h[t];
}

// Per-bin exclusive scan over the 1024 chunks (one block per bin), in place.
// Emits bintot[bin].
__global__ __launch_bounds__(256) void scanA_k(int* __restrict__ bh,
                                               int* __restrict__ bintot) {
  __shared__ int sa[256], sb[256];
  const int t = threadIdx.x;
  int* row = bh + (size_t)blockIdx.x * 1024;
  int v0 = row[t * 4], v1 = row[t * 4 + 1], v2 = row[t * 4 + 2], v3 = row[t * 4 + 3];
  int sum = v0 + v1 + v2 + v3;
  sa[t] = sum;
  __syncthreads();
  int* in = sa;
  int* out = sb;
  for (int st = 1; st < 256; st <<= 1) {
    out[t] = in[t] + (t >= st ? in[t - st] : 0);
    __syncthreads();
    int* tmp = in; in = out; out = tmp;
  }
  int excl = in[t] - sum;
  row[t * 4] = excl;
  row[t * 4 + 1] = excl + v0;
  row[t * 4 + 2] = excl + v0 + v1;
  row[t * 4 + 3] = excl + v0 + v1 + v2;
  if (t == 255) bintot[blockIdx.x] = in[255];
}

// Exclusive scan of the 256 bin totals -> base[256] bucket starts, base[256]=E.
__global__ __launch_bounds__(256) void scanB_k(const int* __restrict__ bintot,
                                               int* __restrict__ base) {
  __shared__ int sa[256], sb[256];
  const int t = threadIdx.x;
  int v = bintot[t];
  sa[t] = v;
  __syncthreads();
  int* in = sa;
  int* out = sb;
  for (int st = 1; st < 256; st <<= 1) {
    out[t] = in[t] + (t >= st ? in[t - st] : 0);
    __syncthreads();
    int* tmp = in; in = out; out = tmp;
  }
  base[t] = in[t] - v;
  if (t == 255) base[256] = in[255];
}

// Pass-0 fill: LDS chunk counting-sort by src>>9, emits parallel (srcS, dstS)
// arrays coarsely sorted by src. Coalesced run write-out, no global scatter.
__global__ __launch_bounds__(256) void sfill_k(const int* __restrict__ src,
                                               const int* __restrict__ dst,
                                               const int* __restrict__ sh,
                                               const int* __restrict__ ssub,
                                               int* __restrict__ srcS,
                                               int* __restrict__ dstS, int E) {
  __shared__ int hA[256], hB[256], runCur[256], gb[256];
  __shared__ int scache[2048];
  __shared__ int dcache[2048];
  __shared__ int sortS[2048];
  __shared__ int sortD[2048];
  __shared__ unsigned short subb[2048];
  const int t = threadIdx.x;
  const int base = blockIdx.x * 2048;
  const int n = min(2048, E - base);
  hA[t] = 0;
  __syncthreads();
#pragma unroll
  for (int j = 0; j < 8; j++) {
    int idx = j * 256 + t;
    int e = base + idx;
    if (idx < n) {
      int s = src[e];
      scache[idx] = s;
      dcache[idx] = dst[e];
      atomicAdd(&hA[s >> 9], 1);
    }
  }
  __syncthreads();
  int cnt = hA[t];
  int* in = hA;
  int* out = hB;
  for (int st = 1; st < 256; st <<= 1) {
    out[t] = in[t] + (t >= st ? in[t - st] : 0);
    __syncthreads();
    int* tmp = in; in = out; out = tmp;
  }
  int rs = in[t] - cnt;
  __syncthreads();
  hB[t] = rs;
  runCur[t] = rs;
  gb[t] = ssub[t] + sh[t * 1024 + blockIdx.x];
  __syncthreads();
#pragma unroll
  for (int j = 0; j < 8; j++) {
    int idx = j * 256 + t;
    if (idx < n) {
      int s = scache[idx];
      int b = s >> 9;
      int lpos = atomicAdd(&runCur[b], 1);
      sortS[lpos] = s;
      sortD[lpos] = dcache[idx];
      subb[lpos] = (unsigned short)b;
    }
  }
  __syncthreads();
  for (int idx = t; idx < n; idx += 256) {
    int b = subb[idx];
    int g = gb[b] + idx - hB[b];
    srcS[g] = sortS[idx];
    dstS[g] = sortD[idx];
  }
}

// Pass-1 fill: LDS chunk counting-sort by dst>>9 reading the src-sorted
// arrays (stable at chunk level -> dst-sub entries stay src-ordered).
// Packed word: (dst&511)<<17 | src  (9b node-in-sub + 17b src, N=2^17).
__global__ __launch_bounds__(256) void bfill1_k(const int* __restrict__ src,
                                                const int* __restrict__ dst,
                                                const int* __restrict__ bh,
                                                const int* __restrict__ sbase,
                                                unsigned int* __restrict__ bkt,
                                                int E) {
  __shared__ int hA[256], hB[256], runCur[256], gb[256];
  __shared__ int dcache[2048];
  __shared__ unsigned int sorted[2048];
  __shared__ unsigned short subb[2048];
  const int t = threadIdx.x;
  const int base = blockIdx.x * 2048;
  const int n = min(2048, E - base);
  hA[t] = 0;
  __syncthreads();
#pragma unroll
  for (int j = 0; j < 8; j++) {
    int idx = j * 256 + t;
    int e = base + idx;
    if (idx < n) {
      int d = dst[e];
      dcache[idx] = d;
      atomicAdd(&hA[d >> 9], 1);
    }
  }
  __syncthreads();
  int cnt = hA[t];
  int* in = hA;
  int* out = hB;
  for (int st = 1; st < 256; st <<= 1) {
    out[t] = in[t] + (t >= st ? in[t - st] : 0);
    __syncthreads();
    int* tmp = in; in = out; out = tmp;
  }
  int rs = in[t] - cnt;
  __syncthreads();
  hB[t] = rs;
  runCur[t] = rs;
  gb[t] = sbase[t] + bh[t * 1024 + blockIdx.x];
  __syncthreads();
#pragma unroll
  for (int j = 0; j < 8; j++) {
    int idx = j * 256 + t;
    int e = base + idx;
    if (idx < n) {
      int d = dcache[idx];
      int b = d >> 9;
      int lpos = atomicAdd(&runCur[b], 1);
      sorted[lpos] = ((unsigned)(d & 511) << 17) | (unsigned)src[e];
      subb[lpos] = (unsigned short)b;
    }
  }
  __syncthreads();
  for (int idx = t; idx < n; idx += 256) {
    int b = subb[idx];
    bkt[gb[b] + idx - hB[b]] = sorted[idx];
  }
}

// Per-sub degree count: block i reads ONLY its own contiguous sub-bucket
// (~8192 entries, 32 iters), LDS histogram, coalesced atomic-free deg write.
__global__ __launch_bounds__(256) void deg4_k(const unsigned int* __restrict__ bkt,
                                              const int* __restrict__ sbase,
                                              int* __restrict__ deg) {
  __shared__ int h[512];
  const int t = threadIdx.x;
  h[t] = 0;
  h[t + 256] = 0;
  __syncthreads();
  const int i = blockIdx.x;
  const int lo = sbase[i], hi = sbase[i + 1];
  for (int e = lo + t; e < hi; e += 256) atomicAdd(&h[bkt[e] >> 17], 1);
  __syncthreads();
  deg[i * 512 + t] = h[t];
  deg[i * 512 + t + 256] = h[t + 256];
}

__global__ __launch_bounds__(256) void blocksum_k(const int* __restrict__ deg,
                                                  int* __restrict__ bsum) {
  __shared__ int sm[256];
  int t = threadIdx.x;
  sm[t] = deg[blockIdx.x * 256 + t];
  __syncthreads();
  for (int s = 128; s > 0; s >>= 1) {
    if (t < s) sm[t] += sm[t + s];
    __syncthreads();
  }
  if (t == 0) bsum[blockIdx.x] = sm[0];
}

// single block: exclusive scan of 512 block sums (in place)
__global__ __launch_bounds__(256) void scanbsum_k(int* __restrict__ bsum) {
  __shared__ int a[512], b[512];
  int t = threadIdx.x;
  a[t] = bsum[t];
  a[t + 256] = bsum[t + 256];
  __syncthreads();
  int* in = a;
  int* out = b;
  for (int st = 1; st < 512; st <<= 1) {
    for (int i = t; i < 512; i += 256) out[i] = in[i] + (i >= st ? in[i - st] : 0);
    __syncthreads();
    int* tmp = in; in = out; out = tmp;
  }
  for (int i = t; i < 512; i += 256) bsum[i] = (i == 0) ? 0 : in[i - 1];
}

// per-block inclusive scan of deg + block offset -> rowPtr (exclusive), fused invdeg
__global__ __launch_bounds__(256) void rowptr_k(const int* __restrict__ deg,
                                                const int* __restrict__ bsumEx,
                                                int* __restrict__ rowPtr,
                                                float* __restrict__ invdeg) {
  __shared__ int a[256], b[256];
  int t = threadIdx.x;
  int i = blockIdx.x * 256 + t;
  int d = deg[i];
  a[t] = d;
  __syncthreads();
  int* in = a;
  int* out = b;
  for (int st = 1; st < 256; st <<= 1) {
    out[t] = in[t] + (t >= st ? in[t - st] : 0);
    __syncthreads();
    int* tmp = in; in = out; out = tmp;
  }
  int incl = in[t] + bsumEx[blockIdx.x];
  rowPtr[i + 1] = incl;
  invdeg[i] = 1.0f / fmaxf((float)d, 1.0f);
  if (i == 0) rowPtr[0] = 0;
}

// Per-sub LDS counting scatter (WRITE_SIZE ~= payload, proven round 4); the
// sequential read preserves the src-sorted order into each node's list.
#define CSR_CAP 12032
__global__ __launch_bounds__(256) void scat4_k(const unsigned int* __restrict__ bkt,
                                               const int* __restrict__ sbase,
                                               const int* __restrict__ rowPtr,
                                               int* __restrict__ csr) {
  __shared__ int cur[512];
  __shared__ int cbuf[CSR_CAP];
  const int t = threadIdx.x;
  const int i = blockIdx.x;
  const int node0 = i * 512;
  const int base0 = rowPtr[node0];
  cur[t] = rowPtr[node0 + t] - base0;
  cur[t + 256] = rowPtr[node0 + t + 256] - base0;
  __syncthreads();
  const int lo = sbase[i], hi = sbase[i + 1];
  for (int e = lo + t; e < hi; e += 256) {
    unsigned v = bkt[e];
    int pos = atomicAdd(&cur[v >> 17], 1);
    int sval = (int)(v & 0x1FFFFu);
    if (pos < CSR_CAP) cbuf[pos] = sval;
    else csr[base0 + pos] = sval;   // never taken for uniform-random input
  }
  __syncthreads();
  const int cnt = rowPtr[node0 + 512] - base0;
  const int lim = cnt < CSR_CAP ? cnt : CSR_CAP;
  for (int idx = t; idx < lim; idx += 256) csr[base0 + idx] = cbuf[idx];
}

// ---- MFMA GEMM: 64 nodes/block, 4 waves x 16-node tile, 16x16x32 bf16 MFMA.
// out1 = fp8_e4m3(x @ W1.T) ; DUAL: out2 = fp32(bias2 + x @ W2.T)
// A-frag: A[m=lane&15][k=quad*8+j] (guide-verified). B pre-packed by wprep_mfma_k.
// C/D: col=lane&15, row=quad*4+reg (m89-verified).
template <int K, int DUAL>
__global__ __launch_bounds__(256) void gemm_mfma_k(const float4* __restrict__ x4,
                                                   const unsigned short* __restrict__ wb1,
                                                   const unsigned short* __restrict__ wb2,
                                                   const float* __restrict__ bias2,
                                                   unsigned char* __restrict__ out1,
                                                   float* __restrict__ out2) {
  constexpr int K4 = K / 4;
  constexpr int LROW = K + 8;   // pad 8 bf16 (16 B) to break fragment-read bank conflicts
  __shared__ unsigned short sxb[64 * LROW];
  const int t = threadIdx.x;
  const int nb = blockIdx.x * 64;
  // stage x (fp32) -> LDS bf16, coalesced float4 reads
#pragma unroll
  for (int idx = t; idx < 64 * K4; idx += 256) {
    int node = idx / K4, k4 = idx - node * K4;
    float4 v = x4[(size_t)(nb + node) * K4 + k4];
    ushort4 h;
    h.x = f2bf(v.x); h.y = f2bf(v.y); h.z = f2bf(v.z); h.w = f2bf(v.w);
    *(ushort4*)&sxb[node * LROW + k4 * 4] = h;
  }
  __syncthreads();
  const int lane = t & 63;
  const int wv = t >> 6;
  const int col = lane & 15;
  const int quad = lane >> 4;
  f32x4v acc1[4], acc2[4];
#pragma unroll
  for (int ct = 0; ct < 4; ct++) {
    acc1[ct] = (f32x4v){0.f, 0.f, 0.f, 0.f};
    if (DUAL) {
      float bj = bias2[ct * 16 + col];
      acc2[ct] = (f32x4v){bj, bj, bj, bj};
    }
  }
#pragma unroll
  for (int s = 0; s < K / 32; s++) {
    bf16x8 a = *(const bf16x8*)&sxb[(wv * 16 + col) * LROW + s * 32 + quad * 8];
#pragma unroll
    for (int ct = 0; ct < 4; ct++) {
      bf16x8 b1 = *(const bf16x8*)&wb1[(size_t)((s * 4 + ct) * 64 + lane) * 8];
      acc1[ct] = __builtin_amdgcn_mfma_f32_16x16x32_bf16(a, b1, acc1[ct], 0, 0, 0);
      if (DUAL) {
        bf16x8 b2 = *(const bf16x8*)&wb2[(size_t)((s * 4 + ct) * 64 + lane) * 8];
        acc2[ct] = __builtin_amdgcn_mfma_f32_16x16x32_bf16(a, b2, acc2[ct], 0, 0, 0);
      }
    }
  }
#pragma unroll
  for (int ct = 0; ct < 4; ct++) {
#pragma unroll
    for (int reg = 0; reg < 4; reg++) {
      int node = nb + wv * 16 + quad * 4 + reg;
      unsigned pk = (unsigned)__builtin_amdgcn_cvt_pk_fp8_f32(acc1[ct][reg],
                                                              acc1[ct][reg], 0, false);
      out1[(size_t)node * 64 + ct * 16 + col] = (unsigned char)(pk & 0xff);
      if (DUAL) out2[(size_t)node * 64 + ct * 16 + col] = acc2[ct][reg];
    }
  }
}

// ---- gather aggregation over fp8 messages — reduction-free lane mapping ----
// lane = (node, quarter): 64 lanes = 16 nodes x 4 x 16-B quarters. Each lane
// serially sums its own 16-fp8 quarter over the node's edge list (now
// src-sorted -> concurrent lanes sweep y coherently, L2-resident cohort).
// Graph-mean partials: one all-lanes-active shfl tree per wave + LDS, written as
// deterministic per-block partials pm[graph][32][64] (no atomics).
template <int WRITE_H>
__global__ __launch_bounds__(256) void gather_k(const uint4* __restrict__ yb,
                                                const int* __restrict__ csr,
                                                const int* __restrict__ rowPtr,
                                                const float* __restrict__ invdeg,
                                                float4* __restrict__ hio,
                                                float* __restrict__ pm) {
  __shared__ float sg[4][4][16];
  const int t = threadIdx.x;
  const int lane = t & 63;
  const int wv = t >> 6;
  const int q = lane & 3;     // 16-B quarter of the 64-B row
  const int nl = lane >> 2;   // node within wave (0..15)
  const int nb = blockIdx.x * 64;   // 64 nodes per block (4 waves x 16)
  const int n = nb + wv * 16 + nl;
  const int rp0 = rowPtr[n], rp1 = rowPtr[n + 1];
  float acc[16];
#pragma unroll
  for (int k = 0; k < 16; k++) acc[k] = 0.f;
  for (int e = rp0; e < rp1; e++) {
    int s = csr[e];
    uint4 v = yb[(size_t)s * 4 + q];
    f32x2 p;
    p = __builtin_amdgcn_cvt_pk_f32_fp8(v.x, false); acc[0] += p.x;  acc[1] += p.y;
    p = __builtin_amdgcn_cvt_pk_f32_fp8(v.x, true);  acc[2] += p.x;  acc[3] += p.y;
    p = __builtin_amdgcn_cvt_pk_f32_fp8(v.y, false); acc[4] += p.x;  acc[5] += p.y;
    p = __builtin_amdgcn_cvt_pk_f32_fp8(v.y, true);  acc[6] += p.x;  acc[7] += p.y;
    p = __builtin_amdgcn_cvt_pk_f32_fp8(v.z, false); acc[8] += p.x;  acc[9] += p.y;
    p = __builtin_amdgcn_cvt_pk_f32_fp8(v.z, true);  acc[10] += p.x; acc[11] += p.y;
    p = __builtin_amdgcn_cvt_pk_f32_fp8(v.w, false); acc[12] += p.x; acc[13] += p.y;
    p = __builtin_amdgcn_cvt_pk_f32_fp8(v.w, true);  acc[14] += p.x; acc[15] += p.y;
  }
  const float sc = invdeg[n];
  float gacc[16];
  if (WRITE_H) {
#pragma unroll
    for (int u = 0; u < 4; u++) {
      float4 o = hio[(size_t)n * 16 + q * 4 + u];
      float4 h = make_float4(acc[4 * u + 0] * sc + o.x, acc[4 * u + 1] * sc + o.y,
                             acc[4 * u + 2] * sc + o.z, acc[4 * u + 3] * sc + o.w);
      hio[(size_t)n * 16 + q * 4 + u] = h;
      gacc[4 * u + 0] = h.x; gacc[4 * u + 1] = h.y;
      gacc[4 * u + 2] = h.z; gacc[4 * u + 3] = h.w;
    }
  } else {
#pragma unroll
    for (int k = 0; k < 16; k++) gacc[k] = acc[k] * sc;
  }
  // reduce across the wave's 16 nodes (lane bits 2..5) — ALL lanes active, uniform
#pragma unroll
  for (int m = 4; m <= 32; m <<= 1)
#pragma unroll
    for (int k = 0; k < 16; k++) gacc[k] += __shfl_xor(gacc[k], m, 64);
  if (nl == 0) {   // lanes 0..3 hold quarter q's wave sum
#pragma unroll
    for (int k = 0; k < 16; k++) sg[wv][q][k] = gacc[k];
  }
  __syncthreads();
  if (t < 64) {   // element j = t
    int qq = t >> 4, k = t & 15;
    float tot = sg[0][qq][k] + sg[1][qq][k] + sg[2][qq][k] + sg[3][qq][k];
    pm[((size_t)(blockIdx.x >> 5) * 32 + (blockIdx.x & 31)) * 64 + t] = tot;
  }
}

// ---- deterministic partial reduce: gm[b][j] = (1/2048) * sum_blk pm[b][blk][j] ----
__global__ __launch_bounds__(256) void reduce_part_k(const float* __restrict__ pm,
                                                     float* __restrict__ gm) {
  int idx = blockIdx.x * 256 + threadIdx.x;   // 4096
  int b = idx >> 6, j = idx & 63;
  float acc = 0.0f;
  for (int blk = 0; blk < 32; blk++) acc += pm[((size_t)b * 32 + blk) * 64 + j];
  gm[idx] = acc * (1.0f / 2048.0f);
}

// ---- g[b][j] = gmean2[b][j] + b2l[j] + sum_k gmean1[b][k] * W2r[j][k] ----
__global__ __launch_bounds__(256) void combine_k(const float* __restrict__ gmean2,
                                                 const float* __restrict__ gmean1,
                                                 const float* __restrict__ b2l,
                                                 const float* __restrict__ W2r,
                                                 float* __restrict__ g) {
  int idx = blockIdx.x * 256 + threadIdx.x;   // 4096
  int b = idx >> 6, j = idx & 63;
  const float4* m4 = (const float4*)(gmean1 + b * 64);
  const float4* w4 = (const float4*)(W2r + j * 64);
  float acc = gmean2[idx] + b2l[j];
#pragma unroll
  for (int k4 = 0; k4 < 16; k4++) {
    float4 mv = m4[k4], wv = w4[k4];
    acc += mv.x * wv.x + mv.y * wv.y + mv.z * wv.z + mv.w * wv.w;
  }
  g[idx] = acc;
}

// ---- h = relu(g @ fc1_W.T + fc1_b)   g:[64,64] fc1_W:[128,64] -> h:[64,128] ----
__global__ __launch_bounds__(256) void mlp1_k(const float* __restrict__ g,
                                              const float* __restrict__ fc1_W,
                                              const float* __restrict__ fc1_b,
                                              float* __restrict__ h) {
  int idx = blockIdx.x * 256 + threadIdx.x;
  int b = idx >> 7, k = idx & 127;
  const float4* g4 = (const float4*)(g + b * 64);
  const float4* w4 = (const float4*)(fc1_W + k * 64);
  float acc = fc1_b[k];
#pragma unroll
  for (int j4 = 0; j4 < 16; j4++) {
    float4 gv = g4[j4], wv = w4[j4];
    acc += gv.x * wv.x + gv.y * wv.y + gv.z * wv.z + gv.w * wv.w;
  }
  h[idx] = fmaxf(acc, 0.0f);
}

// ---- q = h @ fc2_W.T + fc2_b   h:[64,128] fc2_W:[2048,128] -> q:[64,2048] ----
__global__ __launch_bounds__(256) void mlp2_k(const float* __restrict__ h,
                                              const float* __restrict__ fc2_W,
                                              const float* __restrict__ fc2_b,
                                              float* __restrict__ out) {
  __shared__ float4 sh[32];
  int b = blockIdx.x >> 3;
  int a = (blockIdx.x & 7) * 256 + threadIdx.x;
  if (threadIdx.x < 32) sh[threadIdx.x] = ((const float4*)(h + b * 128))[threadIdx.x];
  __syncthreads();
  const float4* w4 = (const float4*)(fc2_W + (size_t)a * 128);
  float acc = fc2_b[a];
#pragma unroll
  for (int k4 = 0; k4 < 32; k4++) {
    float4 hv = sh[k4], wv = w4[k4];
    acc += hv.x * wv.x + hv.y * wv.y + hv.z * wv.z + hv.w * wv.w;
  }
  out[b * 2048 + a] = acc;
}

extern "C" void kernel_launch(void* const* d_in, const int* in_sizes, int n_in,
                              void* d_out, int out_size, void* d_ws, size_t ws_size,
                              hipStream_t stream) {
  const float* x     = (const float*)d_in[0];
  const int*   ei    = (const int*)d_in[1];
  const float* W1l   = (const float*)d_in[2];
  const float* b1l   = (const float*)d_in[3];
  const float* W1r   = (const float*)d_in[4];
  const float* W2l   = (const float*)d_in[5];
  const float* b2l   = (const float*)d_in[6];
  const float* W2r   = (const float*)d_in[7];
  const float* fc1_W = (const float*)d_in[8];
  const float* fc1_b = (const float*)d_in[9];
  const float* fc2_W = (const float*)d_in[10];
  const float* fc2_b = (const float*)d_in[11];
  float* out = (float*)d_out;

  const int N = in_sizes[0] / D_IN;   // 131072
  const int E = in_sizes[1] / 2;      // 2097152
  const int* src = ei;
  const int* dst = ei + E;

  // workspace layout (~62 MiB; 78 MiB proven available)
  char* ws = (char*)d_ws;
  int*   deg    = (int*)ws;     ws += (size_t)N * 4;
  int*   rowPtr = (int*)ws;     ws += (size_t)(N + 256) * 4;
  int*   bsum   = (int*)ws;     ws += 512 * 4;
  float* invdeg = (float*)ws;   ws += (size_t)N * 4;
  float* gmean1 = (float*)ws;   ws += 4096 * 4;
  float* gmean2 = (float*)ws;   ws += 4096 * 4;
  float* g      = (float*)ws;   ws += 4096 * 4;
  float* hbuf   = (float*)ws;   ws += 8192 * 4;
  unsigned short* wb1l = (unsigned short*)ws;  ws += 8192 * 2;  // mfma-packed bf16
  unsigned short* wb1r = (unsigned short*)ws;  ws += 8192 * 2;
  unsigned short* wb2l = (unsigned short*)ws;  ws += 4096 * 2;
  int*   sh     = (int*)ws;     ws += (size_t)256 * 1024 * 4;  // pass-0 [bin][chunk]
  int*   bh     = (int*)ws;     ws += (size_t)256 * 1024 * 4;  // pass-1 [bin][chunk]
  int*   tot    = (int*)ws;     ws += 256 * 4;
  int*   ssub   = (int*)ws;     ws += 260 * 4;    // src-bucket starts [257]
  int*   sbase  = (int*)ws;     ws += 260 * 4;    // dst-sub starts [257]
  float* p1     = (float*)ws;   ws += (size_t)64 * 32 * 64 * 4;  // graph-mean partials
  float* p2     = (float*)ws;   ws += (size_t)64 * 32 * 64 * 4;
  unsigned int* bkt = (unsigned int*)ws;  ws += (size_t)E * 4;   // sub-binned edges
  int*   csr    = (int*)ws;     ws += (size_t)E * 4;
  unsigned char* bufA = (unsigned char*)ws;  ws += (size_t)64 * N;      // y1/y2 fp8
  float* bufB   = (float*)ws;   ws += (size_t)64 * N * 4;  // xr -> h1 (in place, fp32)
  size_t used = (size_t)(ws - (char*)d_ws);

  // Aliases (temporally disjoint): srcS lives in csr (csr written later by
  // scat4), dstS lives in bufA (bufA written later by gemm1).
  int* srcS = csr;
  int* dstS = (int*)bufA;

  // Zero the ENTIRE used workspace every call (round-10 fix: every call must
  // start from the identical, validated-benign state; ~10 us at HBM write BW).
  hipMemsetAsync(d_ws, 0, used, stream);

  wprep_mfma_k<<<4, 256, 0, stream>>>(W1l, wb1l, 128);
  wprep_mfma_k<<<4, 256, 0, stream>>>(W1r, wb1r, 128);
  wprep_mfma_k<<<2, 256, 0, stream>>>(W2l, wb2l, 64);

  // CSR build (round-17): pass-0 coarse src-sort, pass-1 dst-sub sort (order-
  // preserving at chunk level), then per-sub LDS histogram + counting scatter.
  const int nch = (E + 2047) >> 11;   // 1024 for E=2M (hist rows sized 1024)
  bhist1_k<<<nch, 256, 0, stream>>>(src, sh, E);
  scanA_k<<<256, 256, 0, stream>>>(sh, tot);
  scanB_k<<<1, 256, 0, stream>>>(tot, ssub);
  sfill_k<<<nch, 256, 0, stream>>>(src, dst, sh, ssub, srcS, dstS, E);
  bhist1_k<<<nch, 256, 0, stream>>>(dstS, bh, E);
  scanA_k<<<256, 256, 0, stream>>>(bh, tot);
  scanB_k<<<1, 256, 0, stream>>>(tot, sbase);
  bfill1_k<<<nch, 256, 0, stream>>>(srcS, dstS, bh, sbase, bkt, E);
  deg4_k<<<256, 256, 0, stream>>>(bkt, sbase, deg);
  blocksum_k<<<N / 256, 256, 0, stream>>>(deg, bsum);
  scanbsum_k<<<1, 256, 0, stream>>>(bsum);
  rowptr_k<<<N / 256, 256, 0, stream>>>(deg, bsum, rowPtr, invdeg);
  scat4_k<<<256, 256, 0, stream>>>(bkt, sbase, rowPtr, csr);

  // conv1: y1 = fp8(x@W1l.T) -> bufA ; xr = b1l + x@W1r.T -> bufB (fp32)
  gemm_mfma_k<128, 1><<<N / 64, 256, 0, stream>>>((const float4*)x, wb1l, wb1r,
                                                  b1l, bufA, bufB);
  // h1 = gather(y1)*invdeg + xr -> bufB in place; p1 partials
  gather_k<1><<<N / 64, 256, 0, stream>>>((const uint4*)bufA, csr, rowPtr, invdeg,
                                          (float4*)bufB, p1);
  reduce_part_k<<<16, 256, 0, stream>>>(p1, gmean1);

  // conv2: y2 = fp8(h1@W2l.T) -> bufA
  gemm_mfma_k<64, 0><<<N / 64, 256, 0, stream>>>((const float4*)bufB, wb2l, nullptr,
                                                 nullptr, bufA, nullptr);
  // p2 partials of gather(y2)*invdeg  (h2 never materialized)
  gather_k<0><<<N / 64, 256, 0, stream>>>((const uint4*)bufA, csr, rowPtr, invdeg,
                                          nullptr, p2);
  reduce_part_k<<<16, 256, 0, stream>>>(p2, gmean2);

  // g = gmean2 + b2l + gmean1 @ W2r.T
  combine_k<<<16, 256, 0, stream>>>(gmean2, gmean1, b2l, W2r, g);
  mlp1_k<<<32, 256, 0, stream>>>(g, fc1_W, fc1_b, hbuf);
  mlp2_k<<<512, 256, 0, stream>>>(hbuf, fc2_W, fc2_b, out);
}

// Round 7
// 354.486 us; speedup vs baseline: 2.1627x; 1.0019x over previous
//
#include <hip/hip_runtime.h>
#include <hip/hip_bf16.h>

#define D_IN 128
#define D_EMB 64

typedef float f32x2 __attribute__((ext_vector_type(2)));
typedef float f32x4v __attribute__((ext_vector_type(4)));
typedef short bf16x8 __attribute__((ext_vector_type(8)));   // 8 bf16 = 4 VGPRs (guide §3)

static __device__ __forceinline__ unsigned short f2bf(float f) {
  __hip_bfloat16 h = __float2bfloat16(f);
  return *(unsigned short*)&h;
}

// ---- MFMA weight prep: W[64][K] fp32 -> packed bf16 B-fragments.
// frag index tid=(s*4+ct)*64+lane holds W[ct*16+(lane&15)][s*32+(lane>>4)*8 + j], j=0..7
__global__ __launch_bounds__(256) void wprep_mfma_k(const float* __restrict__ W,
                                                    unsigned short* __restrict__ out,
                                                    int K) {
  int tid = blockIdx.x * 256 + threadIdx.x;
  int total = (K / 32) * 4 * 64;
  if (tid >= total) return;
  int lane = tid & 63;
  int ct = (tid >> 6) & 3;
  int s = tid >> 8;
  int row = ct * 16 + (lane & 15);
  int kk = s * 32 + (lane >> 4) * 8;
  unsigned short tmp[8];
#pragma unroll
  for (int j = 0; j < 8; j++) tmp[j] = f2bf(W[row * K + kk + j]);
  *(uint4*)&out[(size_t)tid * 8] = *(uint4*)tmp;
}

// ==== CSR build (round-17 design, proven): src-sort pass 0 + dst-sub sort ====

// Per-chunk 256-bin histogram of key>>9, written TRANSPOSED h[bin*1024+chunk].
__global__ __launch_bounds__(256) void bhist1_k(const int* __restrict__ key,
                                                int* __restrict__ bh, int E) {
  __shared__ int h[256];
  const int t = threadIdx.x;
  h[t] = 0;
  __syncthreads();
  const int base = blockIdx.x * 2048;
#pragma unroll
  for (int j = 0; j < 8; j++) {
    int e = base + j * 256 + t;
    if (e < E) atomicAdd(&h[key[e] >> 9], 1);
  }
  __syncthreads();
  bh[t * 1024 + blockIdx.x] = h[t];
}

// Per-bin exclusive scan over the 1024 chunks (one block per bin), in place.
__global__ __launch_bounds__(256) void scanA_k(int* __restrict__ bh,
                                               int* __restrict__ bintot) {
  __shared__ int sa[256], sb[256];
  const int t = threadIdx.x;
  int* row = bh + (size_t)blockIdx.x * 1024;
  int v0 = row[t * 4], v1 = row[t * 4 + 1], v2 = row[t * 4 + 2], v3 = row[t * 4 + 3];
  int sum = v0 + v1 + v2 + v3;
  sa[t] = sum;
  __syncthreads();
  int* in = sa;
  int* out = sb;
  for (int st = 1; st < 256; st <<= 1) {
    out[t] = in[t] + (t >= st ? in[t - st] : 0);
    __syncthreads();
    int* tmp = in; in = out; out = tmp;
  }
  int excl = in[t] - sum;
  row[t * 4] = excl;
  row[t * 4 + 1] = excl + v0;
  row[t * 4 + 2] = excl + v0 + v1;
  row[t * 4 + 3] = excl + v0 + v1 + v2;
  if (t == 255) bintot[blockIdx.x] = in[255];
}

// Exclusive scan of the 256 bin totals -> base[256] bucket starts, base[256]=E.
__global__ __launch_bounds__(256) void scanB_k(const int* __restrict__ bintot,
                                               int* __restrict__ base) {
  __shared__ int sa[256], sb[256];
  const int t = threadIdx.x;
  int v = bintot[t];
  sa[t] = v;
  __syncthreads();
  int* in = sa;
  int* out = sb;
  for (int st = 1; st < 256; st <<= 1) {
    out[t] = in[t] + (t >= st ? in[t - st] : 0);
    __syncthreads();
    int* tmp = in; in = out; out = tmp;
  }
  base[t] = in[t] - v;
  if (t == 255) base[256] = in[255];
}

// Pass-0 fill: LDS chunk counting-sort by src>>9, emits parallel (srcS, dstS).
__global__ __launch_bounds__(256) void sfill_k(const int* __restrict__ src,
                                               const int* __restrict__ dst,
                                               const int* __restrict__ sh,
                                               const int* __restrict__ ssub,
                                               int* __restrict__ srcS,
                                               int* __restrict__ dstS, int E) {
  __shared__ int hA[256], hB[256], runCur[256], gb[256];
  __shared__ int scache[2048];
  __shared__ int dcache[2048];
  __shared__ int sortS[2048];
  __shared__ int sortD[2048];
  __shared__ unsigned short subb[2048];
  const int t = threadIdx.x;
  const int base = blockIdx.x * 2048;
  const int n = min(2048, E - base);
  hA[t] = 0;
  __syncthreads();
#pragma unroll
  for (int j = 0; j < 8; j++) {
    int idx = j * 256 + t;
    int e = base + idx;
    if (idx < n) {
      int s = src[e];
      scache[idx] = s;
      dcache[idx] = dst[e];
      atomicAdd(&hA[s >> 9], 1);
    }
  }
  __syncthreads();
  int cnt = hA[t];
  int* in = hA;
  int* out = hB;
  for (int st = 1; st < 256; st <<= 1) {
    out[t] = in[t] + (t >= st ? in[t - st] : 0);
    __syncthreads();
    int* tmp = in; in = out; out = tmp;
  }
  int rs = in[t] - cnt;
  __syncthreads();
  hB[t] = rs;
  runCur[t] = rs;
  gb[t] = ssub[t] + sh[t * 1024 + blockIdx.x];
  __syncthreads();
#pragma unroll
  for (int j = 0; j < 8; j++) {
    int idx = j * 256 + t;
    if (idx < n) {
      int s = scache[idx];
      int b = s >> 9;
      int lpos = atomicAdd(&runCur[b], 1);
      sortS[lpos] = s;
      sortD[lpos] = dcache[idx];
      subb[lpos] = (unsigned short)b;
    }
  }
  __syncthreads();
  for (int idx = t; idx < n; idx += 256) {
    int b = subb[idx];
    int g = gb[b] + idx - hB[b];
    srcS[g] = sortS[idx];
    dstS[g] = sortD[idx];
  }
}

// Pass-1 fill: LDS chunk counting-sort by dst>>9 reading the src-sorted
// arrays (stable at chunk level -> dst-sub entries stay src-ordered).
// Packed word: (dst&511)<<17 | src  (9b node-in-sub + 17b src, N=2^17).
__global__ __launch_bounds__(256) void bfill1_k(const int* __restrict__ src,
                                                const int* __restrict__ dst,
                                                const int* __restrict__ bh,
                                                const int* __restrict__ sbase,
                                                unsigned int* __restrict__ bkt,
                                                int E) {
  __shared__ int hA[256], hB[256], runCur[256], gb[256];
  __shared__ int dcache[2048];
  __shared__ unsigned int sorted[2048];
  __shared__ unsigned short subb[2048];
  const int t = threadIdx.x;
  const int base = blockIdx.x * 2048;
  const int n = min(2048, E - base);
  hA[t] = 0;
  __syncthreads();
#pragma unroll
  for (int j = 0; j < 8; j++) {
    int idx = j * 256 + t;
    int e = base + idx;
    if (idx < n) {
      int d = dst[e];
      dcache[idx] = d;
      atomicAdd(&hA[d >> 9], 1);
    }
  }
  __syncthreads();
  int cnt = hA[t];
  int* in = hA;
  int* out = hB;
  for (int st = 1; st < 256; st <<= 1) {
    out[t] = in[t] + (t >= st ? in[t - st] : 0);
    __syncthreads();
    int* tmp = in; in = out; out = tmp;
  }
  int rs = in[t] - cnt;
  __syncthreads();
  hB[t] = rs;
  runCur[t] = rs;
  gb[t] = sbase[t] + bh[t * 1024 + blockIdx.x];
  __syncthreads();
#pragma unroll
  for (int j = 0; j < 8; j++) {
    int idx = j * 256 + t;
    int e = base + idx;
    if (idx < n) {
      int d = dcache[idx];
      int b = d >> 9;
      int lpos = atomicAdd(&runCur[b], 1);
      sorted[lpos] = ((unsigned)(d & 511) << 17) | (unsigned)src[e];
      subb[lpos] = (unsigned short)b;
    }
  }
  __syncthreads();
  for (int idx = t; idx < n; idx += 256) {
    int b = subb[idx];
    bkt[gb[b] + idx - hB[b]] = sorted[idx];
  }
}

// Per-sub degree count (own contiguous sub-bucket, 32 iters, atomic-free write).
__global__ __launch_bounds__(256) void deg4_k(const unsigned int* __restrict__ bkt,
                                              const int* __restrict__ sbase,
                                              int* __restrict__ deg) {
  __shared__ int h[512];
  const int t = threadIdx.x;
  h[t] = 0;
  h[t + 256] = 0;
  __syncthreads();
  const int i = blockIdx.x;
  const int lo = sbase[i], hi = sbase[i + 1];
  for (int e = lo + t; e < hi; e += 256) atomicAdd(&h[bkt[e] >> 17], 1);
  __syncthreads();
  deg[i * 512 + t] = h[t];
  deg[i * 512 + t + 256] = h[t + 256];
}

__global__ __launch_bounds__(256) void blocksum_k(const int* __restrict__ deg,
                                                  int* __restrict__ bsum) {
  __shared__ int sm[256];
  int t = threadIdx.x;
  sm[t] = deg[blockIdx.x * 256 + t];
  __syncthreads();
  for (int s = 128; s > 0; s >>= 1) {
    if (t < s) sm[t] += sm[t + s];
    __syncthreads();
  }
  if (t == 0) bsum[blockIdx.x] = sm[0];
}

// single block: exclusive scan of 512 block sums (in place)
__global__ __launch_bounds__(256) void scanbsum_k(int* __restrict__ bsum) {
  __shared__ int a[512], b[512];
  int t = threadIdx.x;
  a[t] = bsum[t];
  a[t + 256] = bsum[t + 256];
  __syncthreads();
  int* in = a;
  int* out = b;
  for (int st = 1; st < 512; st <<= 1) {
    for (int i = t; i < 512; i += 256) out[i] = in[i] + (i >= st ? in[i - st] : 0);
    __syncthreads();
    int* tmp = in; in = out; out = tmp;
  }
  for (int i = t; i < 512; i += 256) bsum[i] = (i == 0) ? 0 : in[i - 1];
}

// per-block inclusive scan of deg + block offset -> rowPtr (exclusive), fused invdeg
__global__ __launch_bounds__(256) void rowptr_k(const int* __restrict__ deg,
                                                const int* __restrict__ bsumEx,
                                                int* __restrict__ rowPtr,
                                                float* __restrict__ invdeg) {
  __shared__ int a[256], b[256];
  int t = threadIdx.x;
  int i = blockIdx.x * 256 + t;
  int d = deg[i];
  a[t] = d;
  __syncthreads();
  int* in = a;
  int* out = b;
  for (int st = 1; st < 256; st <<= 1) {
    out[t] = in[t] + (t >= st ? in[t - st] : 0);
    __syncthreads();
    int* tmp = in; in = out; out = tmp;
  }
  int incl = in[t] + bsumEx[blockIdx.x];
  rowPtr[i + 1] = incl;
  invdeg[i] = 1.0f / fmaxf((float)d, 1.0f);
  if (i == 0) rowPtr[0] = 0;
}

// Per-sub LDS counting scatter; sequential read preserves src-sorted order.
#define CSR_CAP 12032
__global__ __launch_bounds__(256) void scat4_k(const unsigned int* __restrict__ bkt,
                                               const int* __restrict__ sbase,
                                               const int* __restrict__ rowPtr,
                                               int* __restrict__ csr) {
  __shared__ int cur[512];
  __shared__ int cbuf[CSR_CAP];
  const int t = threadIdx.x;
  const int i = blockIdx.x;
  const int node0 = i * 512;
  const int base0 = rowPtr[node0];
  cur[t] = rowPtr[node0 + t] - base0;
  cur[t + 256] = rowPtr[node0 + t + 256] - base0;
  __syncthreads();
  const int lo = sbase[i], hi = sbase[i + 1];
  for (int e = lo + t; e < hi; e += 256) {
    unsigned v = bkt[e];
    int pos = atomicAdd(&cur[v >> 17], 1);
    int sval = (int)(v & 0x1FFFFu);
    if (pos < CSR_CAP) cbuf[pos] = sval;
    else csr[base0 + pos] = sval;   // never taken for uniform-random input
  }
  __syncthreads();
  const int cnt = rowPtr[node0 + 512] - base0;
  const int lim = cnt < CSR_CAP ? cnt : CSR_CAP;
  for (int idx = t; idx < lim; idx += 256) csr[base0 + idx] = cbuf[idx];
}

// ---- MFMA GEMM, round-18: LDS-FREE. Round-6 profile: 44.5us at MfmaUtil 3.3%,
// VALU 6%, HBM 21%, occupancy 50% -> latency-bound staging+barrier. The LDS
// tile shared NOTHING (A rows are wave-exclusive, B is L1-resident), so load
// A-fragments straight global->VGPR (row=nb+wv*16+(lane&15), 32B/lane/k-slice,
// 128B contiguous per row) with inline f32->bf16 pack. No barrier, no LDS cap.
// ABF16=1 reads a bf16 [N][K] input directly (h1 path).
// out1 = fp8_e4m3(x @ W1.T) ; DUAL: out2 = fp32(bias2 + x @ W2.T)
template <int K, int DUAL, int ABF16>
__global__ __launch_bounds__(256) void gemm_mfma_k(const float4* __restrict__ x4,
                                                   const unsigned short* __restrict__ xb,
                                                   const unsigned short* __restrict__ wb1,
                                                   const unsigned short* __restrict__ wb2,
                                                   const float* __restrict__ bias2,
                                                   unsigned char* __restrict__ out1,
                                                   float* __restrict__ out2) {
  constexpr int K4 = K / 4;
  const int t = threadIdx.x;
  const int lane = t & 63;
  const int wv = t >> 6;
  const int col = lane & 15;
  const int quad = lane >> 4;
  const int nb = blockIdx.x * 64;
  const int arow = nb + wv * 16 + col;   // A-fragment row (m = lane&15)
  f32x4v acc1[4], acc2[4];
#pragma unroll
  for (int ct = 0; ct < 4; ct++) {
    acc1[ct] = (f32x4v){0.f, 0.f, 0.f, 0.f};
    if (DUAL) {
      float bj = bias2[ct * 16 + col];
      acc2[ct] = (f32x4v){bj, bj, bj, bj};
    }
  }
#pragma unroll
  for (int s = 0; s < K / 32; s++) {
    bf16x8 a;
    if (ABF16) {
      a = *(const bf16x8*)&xb[(size_t)arow * K + s * 32 + quad * 8];
    } else {
      float4 f0 = x4[(size_t)arow * K4 + s * 8 + quad * 2];
      float4 f1 = x4[(size_t)arow * K4 + s * 8 + quad * 2 + 1];
      unsigned short h[8];
      h[0] = f2bf(f0.x); h[1] = f2bf(f0.y); h[2] = f2bf(f0.z); h[3] = f2bf(f0.w);
      h[4] = f2bf(f1.x); h[5] = f2bf(f1.y); h[6] = f2bf(f1.z); h[7] = f2bf(f1.w);
      a = *(const bf16x8*)h;
    }
#pragma unroll
    for (int ct = 0; ct < 4; ct++) {
      bf16x8 b1 = *(const bf16x8*)&wb1[(size_t)((s * 4 + ct) * 64 + lane) * 8];
      acc1[ct] = __builtin_amdgcn_mfma_f32_16x16x32_bf16(a, b1, acc1[ct], 0, 0, 0);
      if (DUAL) {
        bf16x8 b2 = *(const bf16x8*)&wb2[(size_t)((s * 4 + ct) * 64 + lane) * 8];
        acc2[ct] = __builtin_amdgcn_mfma_f32_16x16x32_bf16(a, b2, acc2[ct], 0, 0, 0);
      }
    }
  }
#pragma unroll
  for (int ct = 0; ct < 4; ct++) {
#pragma unroll
    for (int reg = 0; reg < 4; reg++) {
      int node = nb + wv * 16 + quad * 4 + reg;
      unsigned pk = (unsigned)__builtin_amdgcn_cvt_pk_fp8_f32(acc1[ct][reg],
                                                              acc1[ct][reg], 0, false);
      out1[(size_t)node * 64 + ct * 16 + col] = (unsigned char)(pk & 0xff);
      if (DUAL) out2[(size_t)node * 64 + ct * 16 + col] = acc2[ct][reg];
    }
  }
}

// ---- gather aggregation over fp8 messages — reduction-free lane mapping ----
// lane = (node, quarter): 64 lanes = 16 nodes x 4 x 16-B quarters; each lane
// serially sums its quarter over the node's src-sorted edge list (concurrent
// lanes sweep y coherently -> L2-resident cohort). WRITE_H: h1 = agg*inv + xr
// written as bf16 (identical rounding point to the old gemm2 LDS stage; pm
// partials still computed from fp32). Graph-mean partials: shfl tree + LDS,
// deterministic per-block partials pm[graph][32][64] (no atomics).
template <int WRITE_H>
__global__ __launch_bounds__(256) void gather_k(const uint4* __restrict__ yb,
                                                const int* __restrict__ csr,
                                                const int* __restrict__ rowPtr,
                                                const float* __restrict__ invdeg,
                                                const float4* __restrict__ xr,
                                                unsigned short* __restrict__ hout,
                                                float* __restrict__ pm) {
  __shared__ float sg[4][4][16];
  const int t = threadIdx.x;
  const int lane = t & 63;
  const int wv = t >> 6;
  const int q = lane & 3;     // 16-B quarter of the 64-B row
  const int nl = lane >> 2;   // node within wave (0..15)
  const int nb = blockIdx.x * 64;   // 64 nodes per block (4 waves x 16)
  const int n = nb + wv * 16 + nl;
  const int rp0 = rowPtr[n], rp1 = rowPtr[n + 1];
  float acc[16];
#pragma unroll
  for (int k = 0; k < 16; k++) acc[k] = 0.f;
  for (int e = rp0; e < rp1; e++) {
    int s = csr[e];
    uint4 v = yb[(size_t)s * 4 + q];
    f32x2 p;
    p = __builtin_amdgcn_cvt_pk_f32_fp8(v.x, false); acc[0] += p.x;  acc[1] += p.y;
    p = __builtin_amdgcn_cvt_pk_f32_fp8(v.x, true);  acc[2] += p.x;  acc[3] += p.y;
    p = __builtin_amdgcn_cvt_pk_f32_fp8(v.y, false); acc[4] += p.x;  acc[5] += p.y;
    p = __builtin_amdgcn_cvt_pk_f32_fp8(v.y, true);  acc[6] += p.x;  acc[7] += p.y;
    p = __builtin_amdgcn_cvt_pk_f32_fp8(v.z, false); acc[8] += p.x;  acc[9] += p.y;
    p = __builtin_amdgcn_cvt_pk_f32_fp8(v.z, true);  acc[10] += p.x; acc[11] += p.y;
    p = __builtin_amdgcn_cvt_pk_f32_fp8(v.w, false); acc[12] += p.x; acc[13] += p.y;
    p = __builtin_amdgcn_cvt_pk_f32_fp8(v.w, true);  acc[14] += p.x; acc[15] += p.y;
  }
  const float sc = invdeg[n];
  float gacc[16];
  if (WRITE_H) {
    unsigned short hh[16];
#pragma unroll
    for (int u = 0; u < 4; u++) {
      float4 o = xr[(size_t)n * 16 + q * 4 + u];
      float v0 = acc[4 * u + 0] * sc + o.x;
      float v1 = acc[4 * u + 1] * sc + o.y;
      float v2 = acc[4 * u + 2] * sc + o.z;
      float v3 = acc[4 * u + 3] * sc + o.w;
      gacc[4 * u + 0] = v0; gacc[4 * u + 1] = v1;
      gacc[4 * u + 2] = v2; gacc[4 * u + 3] = v3;
      hh[4 * u + 0] = f2bf(v0); hh[4 * u + 1] = f2bf(v1);
      hh[4 * u + 2] = f2bf(v2); hh[4 * u + 3] = f2bf(v3);
    }
    *(uint4*)&hout[(size_t)n * 64 + q * 16] = *(uint4*)&hh[0];
    *(uint4*)&hout[(size_t)n * 64 + q * 16 + 8] = *(uint4*)&hh[8];
  } else {
#pragma unroll
    for (int k = 0; k < 16; k++) gacc[k] = acc[k] * sc;
  }
  // reduce across the wave's 16 nodes (lane bits 2..5) — ALL lanes active, uniform
#pragma unroll
  for (int m = 4; m <= 32; m <<= 1)
#pragma unroll
    for (int k = 0; k < 16; k++) gacc[k] += __shfl_xor(gacc[k], m, 64);
  if (nl == 0) {   // lanes 0..3 hold quarter q's wave sum
#pragma unroll
    for (int k = 0; k < 16; k++) sg[wv][q][k] = gacc[k];
  }
  __syncthreads();
  if (t < 64) {   // element j = t
    int qq = t >> 4, k = t & 15;
    float tot = sg[0][qq][k] + sg[1][qq][k] + sg[2][qq][k] + sg[3][qq][k];
    pm[((size_t)(blockIdx.x >> 5) * 32 + (blockIdx.x & 31)) * 64 + t] = tot;
  }
}

// ---- deterministic partial reduce: gm[b][j] = (1/2048) * sum_blk pm[b][blk][j] ----
__global__ __launch_bounds__(256) void reduce_part_k(const float* __restrict__ pm,
                                                     float* __restrict__ gm) {
  int idx = blockIdx.x * 256 + threadIdx.x;   // 4096
  int b = idx >> 6, j = idx & 63;
  float acc = 0.0f;
  for (int blk = 0; blk < 32; blk++) acc += pm[((size_t)b * 32 + blk) * 64 + j];
  gm[idx] = acc * (1.0f / 2048.0f);
}

// ---- g[b][j] = gmean2[b][j] + b2l[j] + sum_k gmean1[b][k] * W2r[j][k] ----
__global__ __launch_bounds__(256) void combine_k(const float* __restrict__ gmean2,
                                                 const float* __restrict__ gmean1,
                                                 const float* __restrict__ b2l,
                                                 const float* __restrict__ W2r,
                                                 float* __restrict__ g) {
  int idx = blockIdx.x * 256 + threadIdx.x;   // 4096
  int b = idx >> 6, j = idx & 63;
  const float4* m4 = (const float4*)(gmean1 + b * 64);
  const float4* w4 = (const float4*)(W2r + j * 64);
  float acc = gmean2[idx] + b2l[j];
#pragma unroll
  for (int k4 = 0; k4 < 16; k4++) {
    float4 mv = m4[k4], wv = w4[k4];
    acc += mv.x * wv.x + mv.y * wv.y + mv.z * wv.z + mv.w * wv.w;
  }
  g[idx] = acc;
}

// ---- h = relu(g @ fc1_W.T + fc1_b)   g:[64,64] fc1_W:[128,64] -> h:[64,128] ----
__global__ __launch_bounds__(256) void mlp1_k(const float* __restrict__ g,
                                              const float* __restrict__ fc1_W,
                                              const float* __restrict__ fc1_b,
                                              float* __restrict__ h) {
  int idx = blockIdx.x * 256 + threadIdx.x;
  int b = idx >> 7, k = idx & 127;
  const float4* g4 = (const float4*)(g + b * 64);
  const float4* w4 = (const float4*)(fc1_W + k * 64);
  float acc = fc1_b[k];
#pragma unroll
  for (int j4 = 0; j4 < 16; j4++) {
    float4 gv = g4[j4], wv = w4[j4];
    acc += gv.x * wv.x + gv.y * wv.y + gv.z * wv.z + gv.w * wv.w;
  }
  h[idx] = fmaxf(acc, 0.0f);
}

// ---- q = h @ fc2_W.T + fc2_b   h:[64,128] fc2_W:[2048,128] -> q:[64,2048] ----
__global__ __launch_bounds__(256) void mlp2_k(const float* __restrict__ h,
                                              const float* __restrict__ fc2_W,
                                              const float* __restrict__ fc2_b,
                                              float* __restrict__ out) {
  __shared__ float4 sh[32];
  int b = blockIdx.x >> 3;
  int a = (blockIdx.x & 7) * 256 + threadIdx.x;
  if (threadIdx.x < 32) sh[threadIdx.x] = ((const float4*)(h + b * 128))[threadIdx.x];
  __syncthreads();
  const float4* w4 = (const float4*)(fc2_W + (size_t)a * 128);
  float acc = fc2_b[a];
#pragma unroll
  for (int k4 = 0; k4 < 32; k4++) {
    float4 hv = sh[k4], wv = w4[k4];
    acc += hv.x * wv.x + hv.y * wv.y + hv.z * wv.z + hv.w * wv.w;
  }
  out[b * 2048 + a] = acc;
}

extern "C" void kernel_launch(void* const* d_in, const int* in_sizes, int n_in,
                              void* d_out, int out_size, void* d_ws, size_t ws_size,
                              hipStream_t stream) {
  const float* x     = (const float*)d_in[0];
  const int*   ei    = (const int*)d_in[1];
  const float* W1l   = (const float*)d_in[2];
  const float* b1l   = (const float*)d_in[3];
  const float* W1r   = (const float*)d_in[4];
  const float* W2l   = (const float*)d_in[5];
  const float* b2l   = (const float*)d_in[6];
  const float* W2r   = (const float*)d_in[7];
  const float* fc1_W = (const float*)d_in[8];
  const float* fc1_b = (const float*)d_in[9];
  const float* fc2_W = (const float*)d_in[10];
  const float* fc2_b = (const float*)d_in[11];
  float* out = (float*)d_out;

  const int N = in_sizes[0] / D_IN;   // 131072
  const int E = in_sizes[1] / 2;      // 2097152
  const int* src = ei;
  const int* dst = ei + E;

  // workspace layout (~77.2 MiB; 78 MiB proven available)
  char* ws = (char*)d_ws;
  int*   deg    = (int*)ws;     ws += (size_t)N * 4;
  int*   rowPtr = (int*)ws;     ws += (size_t)(N + 256) * 4;
  int*   bsum   = (int*)ws;     ws += 512 * 4;
  float* invdeg = (float*)ws;   ws += (size_t)N * 4;
  float* gmean1 = (float*)ws;   ws += 4096 * 4;
  float* gmean2 = (float*)ws;   ws += 4096 * 4;
  float* g      = (float*)ws;   ws += 4096 * 4;
  float* hbuf   = (float*)ws;   ws += 8192 * 4;
  unsigned short* wb1l = (unsigned short*)ws;  ws += 8192 * 2;  // mfma-packed bf16
  unsigned short* wb1r = (unsigned short*)ws;  ws += 8192 * 2;
  unsigned short* wb2l = (unsigned short*)ws;  ws += 4096 * 2;
  int*   sh     = (int*)ws;     ws += (size_t)256 * 1024 * 4;  // pass-0 [bin][chunk]
  int*   bh     = (int*)ws;     ws += (size_t)256 * 1024 * 4;  // pass-1 [bin][chunk]
  int*   tot    = (int*)ws;     ws += 256 * 4;
  int*   ssub   = (int*)ws;     ws += 260 * 4;    // src-bucket starts [257]
  int*   sbase  = (int*)ws;     ws += 260 * 4;    // dst-sub starts [257]
  float* p1     = (float*)ws;   ws += (size_t)64 * 32 * 64 * 4;  // graph-mean partials
  float* p2     = (float*)ws;   ws += (size_t)64 * 32 * 64 * 4;
  unsigned int* bkt = (unsigned int*)ws;  ws += (size_t)E * 4;   // sub-binned edges
  int*   csr    = (int*)ws;     ws += (size_t)E * 4;
  unsigned char* bufA = (unsigned char*)ws;  ws += (size_t)64 * N;      // y1/y2 fp8
  float* bufB   = (float*)ws;   ws += (size_t)64 * N * 4;  // xr (fp32)
  unsigned short* bufC = (unsigned short*)ws;  ws += (size_t)64 * N * 2;  // h1 (bf16)
  size_t used = (size_t)(ws - (char*)d_ws);

  // Aliases (temporally disjoint): srcS lives in csr (csr written later by
  // scat4), dstS lives in bufA (bufA written later by gemm1).
  int* srcS = csr;
  int* dstS = (int*)bufA;

  // Zero the ENTIRE used workspace every call (round-10 fix: every call must
  // start from the identical, validated-benign state; ~12 us at HBM write BW).
  hipMemsetAsync(d_ws, 0, used, stream);

  wprep_mfma_k<<<4, 256, 0, stream>>>(W1l, wb1l, 128);
  wprep_mfma_k<<<4, 256, 0, stream>>>(W1r, wb1r, 128);
  wprep_mfma_k<<<2, 256, 0, stream>>>(W2l, wb2l, 64);

  // CSR build: pass-0 coarse src-sort, pass-1 dst-sub sort (order-preserving
  // at chunk level), then per-sub LDS histogram + counting scatter.
  const int nch = (E + 2047) >> 11;   // 1024 for E=2M (hist rows sized 1024)
  bhist1_k<<<nch, 256, 0, stream>>>(src, sh, E);
  scanA_k<<<256, 256, 0, stream>>>(sh, tot);
  scanB_k<<<1, 256, 0, stream>>>(tot, ssub);
  sfill_k<<<nch, 256, 0, stream>>>(src, dst, sh, ssub, srcS, dstS, E);
  bhist1_k<<<nch, 256, 0, stream>>>(dstS, bh, E);
  scanA_k<<<256, 256, 0, stream>>>(bh, tot);
  scanB_k<<<1, 256, 0, stream>>>(tot, sbase);
  bfill1_k<<<nch, 256, 0, stream>>>(srcS, dstS, bh, sbase, bkt, E);
  deg4_k<<<256, 256, 0, stream>>>(bkt, sbase, deg);
  blocksum_k<<<N / 256, 256, 0, stream>>>(deg, bsum);
  scanbsum_k<<<1, 256, 0, stream>>>(bsum);
  rowptr_k<<<N / 256, 256, 0, stream>>>(deg, bsum, rowPtr, invdeg);
  scat4_k<<<256, 256, 0, stream>>>(bkt, sbase, rowPtr, csr);

  // conv1: y1 = fp8(x@W1l.T) -> bufA ; xr = b1l + x@W1r.T -> bufB (fp32)
  gemm_mfma_k<128, 1, 0><<<N / 64, 256, 0, stream>>>((const float4*)x, nullptr,
                                                     wb1l, wb1r, b1l, bufA, bufB);
  // h1 = bf16(gather(y1)*invdeg + xr) -> bufC ; p1 partials (fp32)
  gather_k<1><<<N / 64, 256, 0, stream>>>((const uint4*)bufA, csr, rowPtr, invdeg,
                                          (const float4*)bufB, bufC, p1);
  reduce_part_k<<<16, 256, 0, stream>>>(p1, gmean1);

  // conv2: y2 = fp8(h1@W2l.T) -> bufA  (A read directly as bf16)
  gemm_mfma_k<64, 0, 1><<<N / 64, 256, 0, stream>>>(nullptr, bufC, wb2l, nullptr,
                                                    nullptr, bufA, nullptr);
  // p2 partials of gather(y2)*invdeg  (h2 never materialized)
  gather_k<0><<<N / 64, 256, 0, stream>>>((const uint4*)bufA, csr, rowPtr, invdeg,
                                          nullptr, nullptr, p2);
  reduce_part_k<<<16, 256, 0, stream>>>(p2, gmean2);

  // g = gmean2 + b2l + gmean1 @ W2r.T
  combine_k<<<16, 256, 0, stream>>>(gmean2, gmean1, b2l, W2r, g);
  mlp1_k<<<32, 256, 0, stream>>>(g, fc1_W, fc1_b, hbuf);
  mlp2_k<<<512, 256, 0, stream>>>(hbuf, fc2_W, fc2_b, out);
}